// Round 3
// baseline (1923.256 us; speedup 1.0000x reference)
//
#include <hip/hip_runtime.h>

typedef short s16x8 __attribute__((ext_vector_type(8)));
typedef float f32x4 __attribute__((ext_vector_type(4)));
typedef unsigned short u16;
typedef unsigned int u32;

__device__ __forceinline__ float bf2f(u16 u) {
  union { unsigned int i; float f; } v; v.i = ((unsigned int)u) << 16; return v.f;
}
__device__ __forceinline__ u16 f2bf(float f) {
  union { float f; unsigned int i; } v; v.f = f;
  unsigned int r = v.i + 0x7fffu + ((v.i >> 16) & 1u);
  return (u16)(r >> 16);
}

// async global->LDS, 16B per lane. LDS dest = wave-uniform base + lane*16.
__device__ __forceinline__ void gload16(const u16* g, u16* l) {
  __builtin_amdgcn_global_load_lds(
      (const __attribute__((address_space(1))) u32*)g,
      (__attribute__((address_space(3))) u32*)l, 16, 0, 0);
}

// ---------------- weight transpose + cast: in[K][N] f32 -> out[N][K] bf16 ----
template<int KDIM, int NDIM>
__launch_bounds__(256)
__global__ void wprep(const float* __restrict__ in, u16* __restrict__ out) {
  __shared__ float t[64][65];
  const int tid = threadIdx.x;
  const int nb = NDIM / 64;
  const int tk0 = (blockIdx.x / nb) * 64;
  const int tn0 = (blockIdx.x % nb) * 64;
#pragma unroll
  for (int i = 0; i < 16; i++) {
    int idx = i * 256 + tid;
    int r = idx >> 6, c = idx & 63;
    t[r][c] = in[(long)(tk0 + r) * NDIM + (tn0 + c)];
  }
  __syncthreads();
#pragma unroll
  for (int i = 0; i < 16; i++) {
    int idx = i * 256 + tid;
    int nn = idx >> 6, kk = idx & 63;
    out[(long)(tn0 + nn) * KDIM + (tk0 + kk)] = f2bf(t[kk][nn]);
  }
}

// ---------------- rmsnorm (f32 src) + cast to bf16 --------------------------
__launch_bounds__(256)
__global__ void rmsnorm_f32(const float* __restrict__ x, const float* __restrict__ w,
                            u16* __restrict__ out) {
  const long row = (long)blockIdx.x * 4 + (threadIdx.x >> 6);
  const int lane = threadIdx.x & 63;
  const float* xr = x + row * 512 + lane * 8;
  float4 v0 = *(const float4*)xr;
  float4 v1 = *(const float4*)(xr + 4);
  float ss = v0.x*v0.x + v0.y*v0.y + v0.z*v0.z + v0.w*v0.w
           + v1.x*v1.x + v1.y*v1.y + v1.z*v1.z + v1.w*v1.w;
#pragma unroll
  for (int o = 1; o < 64; o <<= 1) ss += __shfl_xor(ss, o);
  float sc = rsqrtf(ss * (1.0f / 512.0f) + 1e-6f);
  const float* wp = w + lane * 8;
  float4 w0 = *(const float4*)wp;
  float4 w1 = *(const float4*)(wp + 4);
  union { u16 u[8]; uint4 v; } o;
  o.u[0] = f2bf(v0.x * sc * w0.x);
  o.u[1] = f2bf(v0.y * sc * w0.y);
  o.u[2] = f2bf(v0.z * sc * w0.z);
  o.u[3] = f2bf(v0.w * sc * w0.w);
  o.u[4] = f2bf(v1.x * sc * w1.x);
  o.u[5] = f2bf(v1.y * sc * w1.y);
  o.u[6] = f2bf(v1.z * sc * w1.z);
  o.u[7] = f2bf(v1.w * sc * w1.w);
  *(uint4*)(out + row * 512 + lane * 8) = o.v;
}

// ---------------- rmsnorm (bf16 src) + cast to bf16 -------------------------
__launch_bounds__(256)
__global__ void rmsnorm_bf16(const u16* __restrict__ x, const float* __restrict__ w,
                             u16* __restrict__ out) {
  const long row = (long)blockIdx.x * 4 + (threadIdx.x >> 6);
  const int lane = threadIdx.x & 63;
  uint4 u = *(const uint4*)(x + row * 512 + lane * 8);
  const u16* us = (const u16*)&u;
  float f[8];
  float ss = 0.f;
#pragma unroll
  for (int j = 0; j < 8; j++) { f[j] = bf2f(us[j]); ss += f[j] * f[j]; }
#pragma unroll
  for (int o = 1; o < 64; o <<= 1) ss += __shfl_xor(ss, o);
  float sc = rsqrtf(ss * (1.0f / 512.0f) + 1e-6f);
  const float* wp = w + lane * 8;
  union { u16 u[8]; uint4 v; } o;
#pragma unroll
  for (int j = 0; j < 8; j++) o.u[j] = f2bf(f[j] * sc * wp[j]);
  *(uint4*)(out + row * 512 + lane * 8) = o.v;
}

// ---------------- main GEMM (m97 structure): C[M,Ns] = A @ Bt^T --------------
enum { EPI_BF16 = 0, EPI_PHI = 1, EPI_RESX = 2, EPI_RESH = 3, EPI_OUTF = 5 };

template<int KD, int EPI>
__launch_bounds__(256)
__global__ void gemm_bt(const u16* __restrict__ A, const u16* __restrict__ Bt,
                        void* __restrict__ Cout, const void* __restrict__ aux,
                        int Ns) {
  __shared__ u16 As[128][32];
  __shared__ u16 Bs[128][32];
  const int tid = threadIdx.x;
  const int lane = tid & 63;
  const int wv = tid >> 6;
  // bijective XCD swizzle (all grids have nwg % 8 == 0)
  const int nwgx = gridDim.x;
  int L = blockIdx.y * nwgx + blockIdx.x;
  const int cpx = (nwgx * gridDim.y) >> 3;
  L = (L & 7) * cpx + (L >> 3);
  const long m0 = (long)(L / nwgx) * 128;
  const long n0 = (long)(L % nwgx) * 128;

  const int wr = (wv >> 1) * 64;
  const int wc = (wv & 1) * 64;
  const int fr = lane & 15;
  const int fkb = (lane >> 4) * 8;

  const int srow = lane >> 2;        // 0..15
  const int sch = (lane & 3) * 8;    // element offset within 32-wide K-slab
  const u16* Ag = A + (m0 + wv * 32 + srow) * KD + sch;
  const u16* Bg = Bt + (n0 + wv * 32 + srow) * KD + sch;
  u16* Al0 = &As[wv * 32][0];
  u16* Al1 = &As[wv * 32 + 16][0];
  u16* Bl0 = &Bs[wv * 32][0];
  u16* Bl1 = &Bs[wv * 32 + 16][0];

  f32x4 acc[4][4] = {};
  for (int k0 = 0; k0 < KD; k0 += 32) {
    __syncthreads();
    gload16(Ag + k0, Al0);
    gload16(Ag + k0 + (long)16 * KD, Al1);
    gload16(Bg + k0, Bl0);
    gload16(Bg + k0 + (long)16 * KD, Bl1);
    __syncthreads();
    s16x8 af[4], bfr[4];
#pragma unroll
    for (int i = 0; i < 4; i++) af[i] = *(const s16x8*)&As[wr + i * 16 + fr][fkb];
#pragma unroll
    for (int j = 0; j < 4; j++) bfr[j] = *(const s16x8*)&Bs[wc + j * 16 + fr][fkb];
#pragma unroll
    for (int i = 0; i < 4; i++)
#pragma unroll
      for (int j = 0; j < 4; j++)
        acc[i][j] = __builtin_amdgcn_mfma_f32_16x16x32_bf16(af[i], bfr[j], acc[i][j], 0, 0, 0);
  }

  const int col = lane & 15;
  const int rb = (lane >> 4) * 4;
#pragma unroll
  for (int i = 0; i < 4; i++) {
#pragma unroll
    for (int r = 0; r < 4; r++) {
      long m = m0 + wr + i * 16 + rb + r;
#pragma unroll
      for (int j = 0; j < 4; j++) {
        long n = n0 + wc + j * 16 + col;
        long off = m * Ns + n;
        float v = acc[i][j][r];
        if constexpr (EPI == EPI_BF16) {
          ((u16*)Cout)[off] = f2bf(v);
        } else if constexpr (EPI == EPI_PHI) {
          float p = v > 0.f ? v + 1.f : __expf(v);
          ((u16*)Cout)[off] = f2bf(p);
        } else if constexpr (EPI == EPI_RESX) {
          ((u16*)Cout)[off] = f2bf(((const float*)aux)[off] + v);
        } else if constexpr (EPI == EPI_RESH) {
          ((u16*)Cout)[off] = f2bf(bf2f(((const u16*)aux)[off]) + v);
        } else {  // EPI_OUTF: out f32 = h(bf16) + v
          ((float*)Cout)[off] = bf2f(((const u16*)aux)[off]) + v;
        }
      }
    }
  }
}

// ---------------- fused FFN up: T = silu(A@W1^T) * (A@W3^T) -----------------
__launch_bounds__(256)
__global__ void gemm_ffn_up(const u16* __restrict__ A, const u16* __restrict__ B1t,
                            const u16* __restrict__ B3t, u16* __restrict__ T) {
  constexpr int KD = 512;
  constexpr int Ns = 2048;
  __shared__ u16 As[128][32];
  __shared__ u16 B1s[128][32];
  __shared__ u16 B3s[128][32];
  const int tid = threadIdx.x;
  const int lane = tid & 63;
  const int wv = tid >> 6;
  const int nwgx = gridDim.x;
  int L = blockIdx.y * nwgx + blockIdx.x;
  const int cpx = (nwgx * gridDim.y) >> 3;
  L = (L & 7) * cpx + (L >> 3);
  const long m0 = (long)(L / nwgx) * 128;
  const long n0 = (long)(L % nwgx) * 128;

  const int wr = (wv >> 1) * 64;
  const int wc = (wv & 1) * 64;
  const int fr = lane & 15;
  const int fkb = (lane >> 4) * 8;

  const int srow = lane >> 2;
  const int sch = (lane & 3) * 8;
  const u16* Ag = A + (m0 + wv * 32 + srow) * KD + sch;
  const u16* B1g = B1t + (n0 + wv * 32 + srow) * KD + sch;
  const u16* B3g = B3t + (n0 + wv * 32 + srow) * KD + sch;
  u16* Al0 = &As[wv * 32][0];
  u16* Al1 = &As[wv * 32 + 16][0];
  u16* B1l0 = &B1s[wv * 32][0];
  u16* B1l1 = &B1s[wv * 32 + 16][0];
  u16* B3l0 = &B3s[wv * 32][0];
  u16* B3l1 = &B3s[wv * 32 + 16][0];

  f32x4 a1[4][4] = {}, a3[4][4] = {};
  for (int k0 = 0; k0 < KD; k0 += 32) {
    __syncthreads();
    gload16(Ag + k0, Al0);
    gload16(Ag + k0 + 16 * KD, Al1);
    gload16(B1g + k0, B1l0);
    gload16(B1g + k0 + 16 * KD, B1l1);
    gload16(B3g + k0, B3l0);
    gload16(B3g + k0 + 16 * KD, B3l1);
    __syncthreads();
    s16x8 af[4], b1f[4], b3f[4];
#pragma unroll
    for (int i = 0; i < 4; i++) af[i] = *(const s16x8*)&As[wr + i * 16 + fr][fkb];
#pragma unroll
    for (int j = 0; j < 4; j++) b1f[j] = *(const s16x8*)&B1s[wc + j * 16 + fr][fkb];
#pragma unroll
    for (int j = 0; j < 4; j++) b3f[j] = *(const s16x8*)&B3s[wc + j * 16 + fr][fkb];
#pragma unroll
    for (int i = 0; i < 4; i++)
#pragma unroll
      for (int j = 0; j < 4; j++) {
        a1[i][j] = __builtin_amdgcn_mfma_f32_16x16x32_bf16(af[i], b1f[j], a1[i][j], 0, 0, 0);
        a3[i][j] = __builtin_amdgcn_mfma_f32_16x16x32_bf16(af[i], b3f[j], a3[i][j], 0, 0, 0);
      }
  }

  const int col = lane & 15;
  const int rb = (lane >> 4) * 4;
#pragma unroll
  for (int i = 0; i < 4; i++)
#pragma unroll
    for (int r = 0; r < 4; r++) {
      long m = m0 + wr + i * 16 + rb + r;
#pragma unroll
      for (int j = 0; j < 4; j++) {
        long n = n0 + wc + j * 16 + col;
        float v1 = a1[i][j][r];
        float v3 = a3[i][j][r];
        float s = v1 / (1.f + __expf(-v1));
        T[m * Ns + n] = f2bf(s * v3);
      }
    }
}

// ---------------- fused attention, mode 1 (time): one WG per (b,n,h) --------
__launch_bounds__(256)
__global__ void att_mode1(const u16* __restrict__ q, const u16* __restrict__ k,
                          const u16* __restrict__ v, u16* __restrict__ attc) {
  __shared__ u16 Ks[128][72];
  __shared__ u16 Vs[128][72];
  __shared__ u16 KVT[64][72];
  __shared__ float ksump[4][64];
  __shared__ float ksum_s[64];
  __shared__ float dinv[256];
  const int tid = threadIdx.x;
  const int lane = tid & 63;
  const int w = tid >> 6;
  const int bnh = blockIdx.x;          // ((b*64+n)*8+h)
  const int h = bnh & 7;
  const int bn = bnh >> 3;
  const int n = bn & 63;
  const int b = bn >> 6;
  const long base = ((long)b * 16384 + n) * 512 + h * 64;   // + t*32768
  const int fr = lane & 15;
  const int fk = (lane >> 4) * 8;
  const int sdk = tid & 63, sqq = tid >> 6;

  f32x4 acc[4] = {};
  float ks_acc = 0.f;

  for (int half = 0; half < 2; half++) {
    __syncthreads();
#pragma unroll
    for (int rep = 0; rep < 4; rep++) {
      int idx = rep * 256 + tid;
      int tl = idx >> 3, c8 = idx & 7;
      long go = base + (long)(half * 128 + tl) * 32768 + c8 * 8;
      *(uint4*)&Ks[tl][c8 * 8] = *(const uint4*)(k + go);
      *(uint4*)&Vs[tl][c8 * 8] = *(const uint4*)(v + go);
    }
    __syncthreads();
#pragma unroll
    for (int i = 0; i < 32; i++) ks_acc += bf2f(Ks[sqq * 32 + i][sdk]);
#pragma unroll
    for (int ks = 0; ks < 4; ks++) {
      s16x8 af, bfr[4];
#pragma unroll
      for (int e = 0; e < 8; e++) af[e] = (short)Vs[ks * 32 + fk + e][w * 16 + fr];
#pragma unroll
      for (int j = 0; j < 4; j++)
#pragma unroll
        for (int e = 0; e < 8; e++) bfr[j][e] = (short)Ks[ks * 32 + fk + e][j * 16 + fr];
#pragma unroll
      for (int j = 0; j < 4; j++)
        acc[j] = __builtin_amdgcn_mfma_f32_16x16x32_bf16(af, bfr[j], acc[j], 0, 0, 0);
    }
  }
  ksump[sqq][sdk] = ks_acc;
  __syncthreads();
  {
    const int colL = lane & 15, rb = (lane >> 4) * 4;
#pragma unroll
    for (int j = 0; j < 4; j++)
#pragma unroll
      for (int r = 0; r < 4; r++)
        KVT[w * 16 + rb + r][j * 16 + colL] = f2bf(acc[j][r]);
  }
  if (tid < 64) ksum_s[tid] = ksump[0][tid] + ksump[1][tid] + ksump[2][tid] + ksump[3][tid];
  __syncthreads();
  {
    const u16* qp = q + base + (long)tid * 32768;
    float d = 0.f;
#pragma unroll
    for (int c8 = 0; c8 < 8; c8++) {
      uint4 u = ((const uint4*)qp)[c8];
      const u16* us = (const u16*)&u;
#pragma unroll
      for (int e = 0; e < 8; e++) d += bf2f(us[e]) * ksum_s[c8 * 8 + e];
    }
    dinv[tid] = 0.5f / (d + 1e-6f);
  }
  f32x4 acc2[4][4] = {};
#pragma unroll
  for (int ks = 0; ks < 2; ks++) {
    s16x8 aq[4], bk[4];
#pragma unroll
    for (int i = 0; i < 4; i++)
      aq[i] = *(const s16x8*)(q + base + (long)(w * 64 + i * 16 + fr) * 32768 + ks * 32 + fk);
#pragma unroll
    for (int j = 0; j < 4; j++)
      bk[j] = *(const s16x8*)&KVT[j * 16 + fr][ks * 32 + fk];
#pragma unroll
    for (int i = 0; i < 4; i++)
#pragma unroll
      for (int j = 0; j < 4; j++)
        acc2[i][j] = __builtin_amdgcn_mfma_f32_16x16x32_bf16(aq[i], bk[j], acc2[i][j], 0, 0, 0);
  }
  __syncthreads();
  const int colL = lane & 15, rb = (lane >> 4) * 4;
#pragma unroll
  for (int i = 0; i < 4; i++)
#pragma unroll
    for (int r = 0; r < 4; r++) {
      int t = w * 64 + i * 16 + rb + r;
      float inv = dinv[t];
#pragma unroll
      for (int j = 0; j < 4; j++)
        attc[base + (long)t * 32768 + j * 16 + colL] = f2bf(acc2[i][j][r] * inv);
    }
}

// ---------------- fused attention, mode 2 (entities): one WG per (b,t,h) ----
__launch_bounds__(256)
__global__ void att_mode2(const u16* __restrict__ q, const u16* __restrict__ k,
                          const u16* __restrict__ v, u16* __restrict__ attc) {
  __shared__ u16 Ks[64][72];
  __shared__ u16 Vs[64][72];
  __shared__ u16 KVT[64][72];
  __shared__ float ksump[4][64];
  __shared__ float ksum_s[64];
  __shared__ float dinv[64];
  const int tid = threadIdx.x;
  const int lane = tid & 63;
  const int w = tid >> 6;
  const int bth = blockIdx.x;          // ((b*256+t)*8+h)
  const int h = bth & 7;
  const long bt = bth >> 3;
  const long base = bt * 32768 + h * 64;   // + n*512
  const int fr = lane & 15;
  const int fk = (lane >> 4) * 8;
  const int sdk = tid & 63, sqq = tid >> 6;

#pragma unroll
  for (int rep = 0; rep < 2; rep++) {
    int idx = rep * 256 + tid;
    int nl = idx >> 3, c8 = idx & 7;
    long go = base + (long)nl * 512 + c8 * 8;
    *(uint4*)&Ks[nl][c8 * 8] = *(const uint4*)(k + go);
    *(uint4*)&Vs[nl][c8 * 8] = *(const uint4*)(v + go);
  }
  __syncthreads();
  {
    float s = 0.f;
#pragma unroll
    for (int i = 0; i < 16; i++) s += bf2f(Ks[sqq * 16 + i][sdk]);
    ksump[sqq][sdk] = s;
  }
  f32x4 acc[4] = {};
#pragma unroll
  for (int ks = 0; ks < 2; ks++) {
    s16x8 af, bfr[4];
#pragma unroll
    for (int e = 0; e < 8; e++) af[e] = (short)Vs[ks * 32 + fk + e][w * 16 + fr];
#pragma unroll
    for (int j = 0; j < 4; j++)
#pragma unroll
      for (int e = 0; e < 8; e++) bfr[j][e] = (short)Ks[ks * 32 + fk + e][j * 16 + fr];
#pragma unroll
    for (int j = 0; j < 4; j++)
      acc[j] = __builtin_amdgcn_mfma_f32_16x16x32_bf16(af, bfr[j], acc[j], 0, 0, 0);
  }
  __syncthreads();
  {
    const int colL = lane & 15, rb = (lane >> 4) * 4;
#pragma unroll
    for (int j = 0; j < 4; j++)
#pragma unroll
      for (int r = 0; r < 4; r++)
        KVT[w * 16 + rb + r][j * 16 + colL] = f2bf(acc[j][r]);
  }
  if (tid < 64) ksum_s[tid] = ksump[0][tid] + ksump[1][tid] + ksump[2][tid] + ksump[3][tid];
  __syncthreads();
  if (tid < 64) {
    const u16* qp = q + base + (long)tid * 512;
    float d = 0.f;
#pragma unroll
    for (int c8 = 0; c8 < 8; c8++) {
      uint4 u = ((const uint4*)qp)[c8];
      const u16* us = (const u16*)&u;
#pragma unroll
      for (int e = 0; e < 8; e++) d += bf2f(us[e]) * ksum_s[c8 * 8 + e];
    }
    dinv[tid] = 0.5f / (d + 1e-6f);
  }
  f32x4 acc2[4] = {};
#pragma unroll
  for (int ks = 0; ks < 2; ks++) {
    s16x8 aq, bk[4];
    aq = *(const s16x8*)(q + base + (long)(w * 16 + fr) * 512 + ks * 32 + fk);
#pragma unroll
    for (int j = 0; j < 4; j++)
      bk[j] = *(const s16x8*)&KVT[j * 16 + fr][ks * 32 + fk];
#pragma unroll
    for (int j = 0; j < 4; j++)
      acc2[j] = __builtin_amdgcn_mfma_f32_16x16x32_bf16(aq, bk[j], acc2[j], 0, 0, 0);
  }
  __syncthreads();
  const int colL = lane & 15, rb = (lane >> 4) * 4;
#pragma unroll
  for (int r = 0; r < 4; r++) {
    int nr = w * 16 + rb + r;
    float inv = dinv[nr];
#pragma unroll
    for (int j = 0; j < 4; j++) {
      long o = base + (long)nr * 512 + j * 16 + colL;
      attc[o] = f2bf(bf2f(attc[o]) + acc2[j][r] * inv);
    }
  }
}

// ============================================================================
extern "C" void kernel_launch(void* const* d_in, const int* in_sizes, int n_in,
                              void* d_out, int out_size, void* d_ws, size_t ws_size,
                              hipStream_t stream) {
  const float* X    = (const float*)d_in[0];
  const float* Z    = (const float*)d_in[1];
  const float* n1   = (const float*)d_in[2];
  const float* n2   = (const float*)d_in[3];
  const float* n3   = (const float*)d_in[4];
  const float* nz   = (const float*)d_in[5];
  const float* a_wq = (const float*)d_in[6];
  const float* a_wk = (const float*)d_in[7];
  const float* a_wv = (const float*)d_in[8];
  const float* a_wo = (const float*)d_in[9];
  const float* c_wq = (const float*)d_in[10];
  const float* c_wk = (const float*)d_in[11];
  const float* c_wv = (const float*)d_in[12];
  const float* c_wo = (const float*)d_in[13];
  const float* f_w1 = (const float*)d_in[14];
  const float* f_w2 = (const float*)d_in[15];
  const float* f_w3 = (const float*)d_in[16];
  float* out = (float*)d_out;
  (void)ws_size; (void)in_sizes; (void)n_in; (void)out_size;

  char* p = (char*)d_ws;
  size_t off = 0;
  auto take = [&](size_t bytes) -> char* {
    char* r = p + off;
    off += (bytes + 255) & ~(size_t)255;
    return r;
  };
  // ws buffers (total ~218 MiB)
  u16* w_aq = (u16*)take(512 * 512 * 2);
  u16* w_ak = (u16*)take(512 * 512 * 2);
  u16* w_av = (u16*)take(512 * 512 * 2);
  u16* w_ao = (u16*)take(512 * 512 * 2);
  u16* w_cq = (u16*)take(512 * 512 * 2);
  u16* w_ck = (u16*)take(512 * 512 * 2);
  u16* w_cv = (u16*)take(512 * 512 * 2);
  u16* w_co = (u16*)take(512 * 512 * 2);
  u16* w_f1 = (u16*)take(2048 * 512 * 2);
  u16* w_f3 = (u16*)take(2048 * 512 * 2);
  u16* w_f2 = (u16*)take(512 * 2048 * 2);
  u16* hbuf = (u16*)take((size_t)65536 * 512 * 2);   // 64 MiB, bf16 residual h
  u16* qbuf = (u16*)take((size_t)65536 * 512 * 2);   // 64 MiB; FFN hidden chunk
  u16* kbuf = (u16*)take((size_t)65536 * 512 * 2);   // 64 MiB
  u16* nstg = (u16*)take((size_t)16384 * 512 * 2);   // 16 MiB norm-chunk staging
  // d_out as scratch (128 MiB): v | attc  (both dead before phase 3 writes)
  u16* vbuf = (u16*)d_out;
  u16* attc = (u16*)d_out + (size_t)65536 * 512;
  u16* tslot = qbuf;   // FFN: [16384][2048] bf16 chunk = 64 MiB

  dim3 b256(256);
  const int CH = 16384;          // rows per chunk
  dim3 gN(4, CH / 128);          // Ns=512 chunk GEMM  (512 blocks)
  dim3 gF(16, CH / 128);         // Ns=2048 chunk GEMM (2048 blocks)
  dim3 gFull(4, 512);            // Ns=512 full-M GEMM (2048 blocks)

  // weight prep
  wprep<512, 512><<<64, b256, 0, stream>>>(a_wq, w_aq);
  wprep<512, 512><<<64, b256, 0, stream>>>(a_wk, w_ak);
  wprep<512, 512><<<64, b256, 0, stream>>>(a_wv, w_av);
  wprep<512, 512><<<64, b256, 0, stream>>>(a_wo, w_ao);
  wprep<512, 512><<<64, b256, 0, stream>>>(c_wq, w_cq);
  wprep<512, 512><<<64, b256, 0, stream>>>(c_wk, w_ck);
  wprep<512, 512><<<64, b256, 0, stream>>>(c_wv, w_cv);
  wprep<512, 512><<<64, b256, 0, stream>>>(c_wo, w_co);
  wprep<512, 2048><<<256, b256, 0, stream>>>(f_w1, w_f1);
  wprep<512, 2048><<<256, b256, 0, stream>>>(f_w3, w_f3);
  wprep<2048, 512><<<256, b256, 0, stream>>>(f_w2, w_f2);

  // ---------------- Phase 1: h = X + SelfAtt(norm1(X)) ----------------------
  for (int c = 0; c < 4; c++) {
    const size_t ro = (size_t)c * CH * 512;
    rmsnorm_f32<<<CH / 4, b256, 0, stream>>>(X + ro, n1, nstg);
    gemm_bt<512, EPI_PHI><<<gN, b256, 0, stream>>>(nstg, w_aq, qbuf + ro, nullptr, 512);
    gemm_bt<512, EPI_PHI><<<gN, b256, 0, stream>>>(nstg, w_ak, kbuf + ro, nullptr, 512);
    gemm_bt<512, EPI_BF16><<<gN, b256, 0, stream>>>(nstg, w_av, vbuf + ro, nullptr, 512);
  }
  att_mode1<<<2048, b256, 0, stream>>>(qbuf, kbuf, vbuf, attc);
  att_mode2<<<8192, b256, 0, stream>>>(qbuf, kbuf, vbuf, attc);
  gemm_bt<512, EPI_RESX><<<gFull, b256, 0, stream>>>(attc, w_ao, hbuf, X, 512);

  // ---------------- Phase 2: h += CrossAtt(norm3(h), normz(Z)) --------------
  for (int c = 0; c < 4; c++) {
    const size_t ro = (size_t)c * CH * 512;
    rmsnorm_bf16<<<CH / 4, b256, 0, stream>>>(hbuf + ro, n3, nstg);
    gemm_bt<512, EPI_PHI><<<gN, b256, 0, stream>>>(nstg, w_cq, qbuf + ro, nullptr, 512);
    rmsnorm_f32<<<CH / 4, b256, 0, stream>>>(Z + ro, nz, nstg);
    gemm_bt<512, EPI_PHI><<<gN, b256, 0, stream>>>(nstg, w_ck, kbuf + ro, nullptr, 512);
    gemm_bt<512, EPI_BF16><<<gN, b256, 0, stream>>>(nstg, w_cv, vbuf + ro, nullptr, 512);
  }
  att_mode1<<<2048, b256, 0, stream>>>(qbuf, kbuf, vbuf, attc);
  att_mode2<<<8192, b256, 0, stream>>>(qbuf, kbuf, vbuf, attc);
  gemm_bt<512, EPI_RESH><<<gFull, b256, 0, stream>>>(attc, w_co, hbuf, hbuf, 512);

  // ---------------- Phase 3: out = h + SwiGLU(norm2(h)) ---------------------
  for (int c = 0; c < 4; c++) {
    const size_t ro = (size_t)c * CH * 512;
    rmsnorm_bf16<<<CH / 4, b256, 0, stream>>>(hbuf + ro, n2, nstg);
    gemm_ffn_up<<<gF, b256, 0, stream>>>(nstg, w_f1, w_f3, tslot);
    gemm_bt<2048, EPI_OUTF><<<gN, b256, 0, stream>>>(tslot, w_f2, out + ro, hbuf + ro, 512);
  }
}

// Round 4
// 1714.320 us; speedup vs baseline: 1.1219x; 1.1219x over previous
//
#include <hip/hip_runtime.h>

typedef short s16x8 __attribute__((ext_vector_type(8)));
typedef float f32x4 __attribute__((ext_vector_type(4)));
typedef unsigned short u16;
typedef unsigned int u32;

__device__ __forceinline__ float bf2f(u16 u) {
  union { unsigned int i; float f; } v; v.i = ((unsigned int)u) << 16; return v.f;
}
__device__ __forceinline__ u16 f2bf(float f) {
  union { float f; unsigned int i; } v; v.f = f;
  unsigned int r = v.i + 0x7fffu + ((v.i >> 16) & 1u);
  return (u16)(r >> 16);
}

// async global->LDS, 16B per lane. LDS dest must be wave-uniform; HW adds lane*16.
__device__ __forceinline__ void gload16(const u16* g, u16* l) {
  __builtin_amdgcn_global_load_lds(
      (const __attribute__((address_space(1))) u32*)g,
      (__attribute__((address_space(3))) u32*)l, 16, 0, 0);
}

// ---------------- weight transpose + cast: in[K][N] f32 -> out[N][K] bf16 ----
template<int KDIM, int NDIM>
__launch_bounds__(256)
__global__ void wprep(const float* __restrict__ in, u16* __restrict__ out) {
  __shared__ float t[64][65];
  const int tid = threadIdx.x;
  const int nb = NDIM / 64;
  const int tk0 = (blockIdx.x / nb) * 64;
  const int tn0 = (blockIdx.x % nb) * 64;
#pragma unroll
  for (int i = 0; i < 16; i++) {
    int idx = i * 256 + tid;
    int r = idx >> 6, c = idx & 63;
    t[r][c] = in[(long)(tk0 + r) * NDIM + (tn0 + c)];
  }
  __syncthreads();
#pragma unroll
  for (int i = 0; i < 16; i++) {
    int idx = i * 256 + tid;
    int nn = idx >> 6, kk = idx & 63;
    out[(long)(tn0 + nn) * KDIM + (tk0 + kk)] = f2bf(t[kk][nn]);
  }
}

// ---------------- rmsnorm (f32 src) + cast to bf16 --------------------------
__launch_bounds__(256)
__global__ void rmsnorm_f32(const float* __restrict__ x, const float* __restrict__ w,
                            u16* __restrict__ out) {
  const long row = (long)blockIdx.x * 4 + (threadIdx.x >> 6);
  const int lane = threadIdx.x & 63;
  const float* xr = x + row * 512 + lane * 8;
  float4 v0 = *(const float4*)xr;
  float4 v1 = *(const float4*)(xr + 4);
  float ss = v0.x*v0.x + v0.y*v0.y + v0.z*v0.z + v0.w*v0.w
           + v1.x*v1.x + v1.y*v1.y + v1.z*v1.z + v1.w*v1.w;
#pragma unroll
  for (int o = 1; o < 64; o <<= 1) ss += __shfl_xor(ss, o);
  float sc = rsqrtf(ss * (1.0f / 512.0f) + 1e-6f);
  const float* wp = w + lane * 8;
  float4 w0 = *(const float4*)wp;
  float4 w1 = *(const float4*)(wp + 4);
  union { u16 u[8]; uint4 v; } o;
  o.u[0] = f2bf(v0.x * sc * w0.x);
  o.u[1] = f2bf(v0.y * sc * w0.y);
  o.u[2] = f2bf(v0.z * sc * w0.z);
  o.u[3] = f2bf(v0.w * sc * w0.w);
  o.u[4] = f2bf(v1.x * sc * w1.x);
  o.u[5] = f2bf(v1.y * sc * w1.y);
  o.u[6] = f2bf(v1.z * sc * w1.z);
  o.u[7] = f2bf(v1.w * sc * w1.w);
  *(uint4*)(out + row * 512 + lane * 8) = o.v;
}

// ---------------- rmsnorm (bf16 src) + cast to bf16 -------------------------
__launch_bounds__(256)
__global__ void rmsnorm_bf16(const u16* __restrict__ x, const float* __restrict__ w,
                             u16* __restrict__ out) {
  const long row = (long)blockIdx.x * 4 + (threadIdx.x >> 6);
  const int lane = threadIdx.x & 63;
  uint4 u = *(const uint4*)(x + row * 512 + lane * 8);
  const u16* us = (const u16*)&u;
  float f[8];
  float ss = 0.f;
#pragma unroll
  for (int j = 0; j < 8; j++) { f[j] = bf2f(us[j]); ss += f[j] * f[j]; }
#pragma unroll
  for (int o = 1; o < 64; o <<= 1) ss += __shfl_xor(ss, o);
  float sc = rsqrtf(ss * (1.0f / 512.0f) + 1e-6f);
  const float* wp = w + lane * 8;
  union { u16 u[8]; uint4 v; } o;
#pragma unroll
  for (int j = 0; j < 8; j++) o.u[j] = f2bf(f[j] * sc * wp[j]);
  *(uint4*)(out + row * 512 + lane * 8) = o.v;
}

// ---------------- 2-phase double-buffered GEMM: C[M,Ns] = A @ Bt^T -----------
enum { EPI_BF16 = 0, EPI_PHI = 1, EPI_RESX = 2, EPI_RESH = 3, EPI_SILUMUL = 4, EPI_OUTF = 5 };

template<int KD, int EPI>
__launch_bounds__(256)
__global__ void gemm2(const u16* __restrict__ A, const u16* __restrict__ Bt,
                      void* __restrict__ Cout, const void* __restrict__ aux,
                      int Ns) {
  __shared__ u16 As[2][128][64];
  __shared__ u16 Bs[2][128][64];
  const int tid = threadIdx.x;
  const int lane = tid & 63;
  const int wv = tid >> 6;
  // bijective XCD swizzle (all grids have nwg % 8 == 0)
  const int nwgx = gridDim.x;
  int L = blockIdx.y * nwgx + blockIdx.x;
  const int cpx = (nwgx * gridDim.y) >> 3;
  L = (L & 7) * cpx + (L >> 3);
  const long m0 = (long)(L / nwgx) * 128;
  const long n0 = (long)(L % nwgx) * 128;

  const int wr = (wv >> 1) * 64;
  const int wc = (wv & 1) * 64;
  const int fr = lane & 15;
  const int fkb = (lane >> 4) * 8;

  // staging: per instr i, wave covers rows [(i*4+wv)*8, +8) x 64 k-elems (1 KiB)
  const u16* Ag = A + (m0 + (lane >> 3)) * KD + (lane & 7) * 8;
  const u16* Bg = Bt + (n0 + (lane >> 3)) * KD + (lane & 7) * 8;

  f32x4 acc[4][4] = {};

  auto STAGE = [&](int b, int k0) {
#pragma unroll
    for (int i = 0; i < 4; i++) {
      const int r8 = (i * 4 + wv) * 8;
      gload16(Ag + (long)r8 * KD + k0, &As[b][r8][0]);
      gload16(Bg + (long)r8 * KD + k0, &Bs[b][r8][0]);
    }
  };
  auto COMPUTE = [&](int b) {
#pragma unroll
    for (int ks = 0; ks < 2; ks++) {
      s16x8 af[4], bf[4];
#pragma unroll
      for (int i = 0; i < 4; i++) af[i] = *(const s16x8*)&As[b][wr + i * 16 + fr][ks * 32 + fkb];
#pragma unroll
      for (int j = 0; j < 4; j++) bf[j] = *(const s16x8*)&Bs[b][wc + j * 16 + fr][ks * 32 + fkb];
#pragma unroll
      for (int i = 0; i < 4; i++)
#pragma unroll
        for (int j = 0; j < 4; j++)
          acc[i][j] = __builtin_amdgcn_mfma_f32_16x16x32_bf16(af[i], bf[j], acc[i][j], 0, 0, 0);
    }
  };

  constexpr int NT = KD / 64;
  STAGE(0, 0);
  __syncthreads();
#pragma unroll 1
  for (int kt = 0; kt < NT - 2; kt += 2) {
    STAGE(1, (kt + 1) * 64);   // prefetch next tile while computing current
    COMPUTE(0);
    __syncthreads();           // implicit vmcnt(0): stage done, reads done
    STAGE(0, (kt + 2) * 64);
    COMPUTE(1);
    __syncthreads();
  }
  STAGE(1, (NT - 1) * 64);
  COMPUTE(0);
  __syncthreads();
  COMPUTE(1);

  const int col = lane & 15;
  const int rb = (lane >> 4) * 4;
#pragma unroll
  for (int i = 0; i < 4; i++) {
#pragma unroll
    for (int r = 0; r < 4; r++) {
      long m = m0 + wr + i * 16 + rb + r;
#pragma unroll
      for (int j = 0; j < 4; j++) {
        long n = n0 + wc + j * 16 + col;
        long off = m * Ns + n;
        float v = acc[i][j][r];
        if constexpr (EPI == EPI_BF16) {
          ((u16*)Cout)[off] = f2bf(v);
        } else if constexpr (EPI == EPI_PHI) {
          float p = v > 0.f ? v + 1.f : __expf(v);
          ((u16*)Cout)[off] = f2bf(p);
        } else if constexpr (EPI == EPI_RESX) {
          ((u16*)Cout)[off] = f2bf(((const float*)aux)[off] + v);
        } else if constexpr (EPI == EPI_RESH) {
          ((u16*)Cout)[off] = f2bf(bf2f(((const u16*)aux)[off]) + v);
        } else if constexpr (EPI == EPI_SILUMUL) {
          float t = bf2f(((const u16*)aux)[off]);
          float s = t / (1.f + __expf(-t));
          ((u16*)Cout)[off] = f2bf(s * v);
        } else {  // EPI_OUTF: out f32 = h(bf16) + v
          ((float*)Cout)[off] = bf2f(((const u16*)aux)[off]) + v;
        }
      }
    }
  }
}

// ---------------- fused attention, mode 1 (time): one WG per (b,n,h) --------
__launch_bounds__(256)
__global__ void att_mode1(const u16* __restrict__ q, const u16* __restrict__ k,
                          const u16* __restrict__ v, u16* __restrict__ attc) {
  __shared__ u16 Ks[128][72];
  __shared__ u16 Vs[128][72];
  __shared__ u16 KVT[64][72];
  __shared__ float ksump[4][64];
  __shared__ float ksum_s[64];
  __shared__ float dinv[256];
  const int tid = threadIdx.x;
  const int lane = tid & 63;
  const int w = tid >> 6;
  const int bnh = blockIdx.x;          // ((b*64+n)*8+h)
  const int h = bnh & 7;
  const int bn = bnh >> 3;
  const int n = bn & 63;
  const int b = bn >> 6;
  const long base = ((long)b * 16384 + n) * 512 + h * 64;   // + t*32768
  const int fr = lane & 15;
  const int fk = (lane >> 4) * 8;
  const int sdk = tid & 63, sqq = tid >> 6;

  f32x4 acc[4] = {};
  float ks_acc = 0.f;

  for (int half = 0; half < 2; half++) {
    __syncthreads();
#pragma unroll
    for (int rep = 0; rep < 4; rep++) {
      int idx = rep * 256 + tid;
      int tl = idx >> 3, c8 = idx & 7;
      long go = base + (long)(half * 128 + tl) * 32768 + c8 * 8;
      *(uint4*)&Ks[tl][c8 * 8] = *(const uint4*)(k + go);
      *(uint4*)&Vs[tl][c8 * 8] = *(const uint4*)(v + go);
    }
    __syncthreads();
#pragma unroll
    for (int i = 0; i < 32; i++) ks_acc += bf2f(Ks[sqq * 32 + i][sdk]);
#pragma unroll
    for (int ks = 0; ks < 4; ks++) {
      s16x8 af, bfr[4];
#pragma unroll
      for (int e = 0; e < 8; e++) af[e] = (short)Vs[ks * 32 + fk + e][w * 16 + fr];
#pragma unroll
      for (int j = 0; j < 4; j++)
#pragma unroll
        for (int e = 0; e < 8; e++) bfr[j][e] = (short)Ks[ks * 32 + fk + e][j * 16 + fr];
#pragma unroll
      for (int j = 0; j < 4; j++)
        acc[j] = __builtin_amdgcn_mfma_f32_16x16x32_bf16(af, bfr[j], acc[j], 0, 0, 0);
    }
  }
  ksump[sqq][sdk] = ks_acc;
  __syncthreads();
  {
    const int colL = lane & 15, rb = (lane >> 4) * 4;
#pragma unroll
    for (int j = 0; j < 4; j++)
#pragma unroll
      for (int r = 0; r < 4; r++)
        KVT[w * 16 + rb + r][j * 16 + colL] = f2bf(acc[j][r]);
  }
  if (tid < 64) ksum_s[tid] = ksump[0][tid] + ksump[1][tid] + ksump[2][tid] + ksump[3][tid];
  __syncthreads();
  {
    const u16* qp = q + base + (long)tid * 32768;
    float d = 0.f;
#pragma unroll
    for (int c8 = 0; c8 < 8; c8++) {
      uint4 u = ((const uint4*)qp)[c8];
      const u16* us = (const u16*)&u;
#pragma unroll
      for (int e = 0; e < 8; e++) d += bf2f(us[e]) * ksum_s[c8 * 8 + e];
    }
    dinv[tid] = 0.5f / (d + 1e-6f);
  }
  f32x4 acc2[4][4] = {};
#pragma unroll
  for (int ks = 0; ks < 2; ks++) {
    s16x8 aq[4], bk[4];
#pragma unroll
    for (int i = 0; i < 4; i++)
      aq[i] = *(const s16x8*)(q + base + (long)(w * 64 + i * 16 + fr) * 32768 + ks * 32 + fk);
#pragma unroll
    for (int j = 0; j < 4; j++)
      bk[j] = *(const s16x8*)&KVT[j * 16 + fr][ks * 32 + fk];
#pragma unroll
    for (int i = 0; i < 4; i++)
#pragma unroll
      for (int j = 0; j < 4; j++)
        acc2[i][j] = __builtin_amdgcn_mfma_f32_16x16x32_bf16(aq[i], bk[j], acc2[i][j], 0, 0, 0);
  }
  __syncthreads();
  const int colL = lane & 15, rb = (lane >> 4) * 4;
#pragma unroll
  for (int i = 0; i < 4; i++)
#pragma unroll
    for (int r = 0; r < 4; r++) {
      int t = w * 64 + i * 16 + rb + r;
      float inv = dinv[t];
#pragma unroll
      for (int j = 0; j < 4; j++)
        attc[base + (long)t * 32768 + j * 16 + colL] = f2bf(acc2[i][j][r] * inv);
    }
}

// ---------------- fused attention, mode 2 (entities): one WG per (b,t,h) ----
__launch_bounds__(256)
__global__ void att_mode2(const u16* __restrict__ q, const u16* __restrict__ k,
                          const u16* __restrict__ v, u16* __restrict__ attc) {
  __shared__ u16 Ks[64][72];
  __shared__ u16 Vs[64][72];
  __shared__ u16 KVT[64][72];
  __shared__ float ksump[4][64];
  __shared__ float ksum_s[64];
  __shared__ float dinv[64];
  const int tid = threadIdx.x;
  const int lane = tid & 63;
  const int w = tid >> 6;
  const int bth = blockIdx.x;          // ((b*256+t)*8+h)
  const int h = bth & 7;
  const long bt = bth >> 3;
  const long base = bt * 32768 + h * 64;   // + n*512
  const int fr = lane & 15;
  const int fk = (lane >> 4) * 8;
  const int sdk = tid & 63, sqq = tid >> 6;

#pragma unroll
  for (int rep = 0; rep < 2; rep++) {
    int idx = rep * 256 + tid;
    int nl = idx >> 3, c8 = idx & 7;
    long go = base + (long)nl * 512 + c8 * 8;
    *(uint4*)&Ks[nl][c8 * 8] = *(const uint4*)(k + go);
    *(uint4*)&Vs[nl][c8 * 8] = *(const uint4*)(v + go);
  }
  __syncthreads();
  {
    float s = 0.f;
#pragma unroll
    for (int i = 0; i < 16; i++) s += bf2f(Ks[sqq * 16 + i][sdk]);
    ksump[sqq][sdk] = s;
  }
  f32x4 acc[4] = {};
#pragma unroll
  for (int ks = 0; ks < 2; ks++) {
    s16x8 af, bfr[4];
#pragma unroll
    for (int e = 0; e < 8; e++) af[e] = (short)Vs[ks * 32 + fk + e][w * 16 + fr];
#pragma unroll
    for (int j = 0; j < 4; j++)
#pragma unroll
      for (int e = 0; e < 8; e++) bfr[j][e] = (short)Ks[ks * 32 + fk + e][j * 16 + fr];
#pragma unroll
    for (int j = 0; j < 4; j++)
      acc[j] = __builtin_amdgcn_mfma_f32_16x16x32_bf16(af, bfr[j], acc[j], 0, 0, 0);
  }
  __syncthreads();
  {
    const int colL = lane & 15, rb = (lane >> 4) * 4;
#pragma unroll
    for (int j = 0; j < 4; j++)
#pragma unroll
      for (int r = 0; r < 4; r++)
        KVT[w * 16 + rb + r][j * 16 + colL] = f2bf(acc[j][r]);
  }
  if (tid < 64) ksum_s[tid] = ksump[0][tid] + ksump[1][tid] + ksump[2][tid] + ksump[3][tid];
  __syncthreads();
  if (tid < 64) {
    const u16* qp = q + base + (long)tid * 512;
    float d = 0.f;
#pragma unroll
    for (int c8 = 0; c8 < 8; c8++) {
      uint4 u = ((const uint4*)qp)[c8];
      const u16* us = (const u16*)&u;
#pragma unroll
      for (int e = 0; e < 8; e++) d += bf2f(us[e]) * ksum_s[c8 * 8 + e];
    }
    dinv[tid] = 0.5f / (d + 1e-6f);
  }
  f32x4 acc2[4] = {};
#pragma unroll
  for (int ks = 0; ks < 2; ks++) {
    s16x8 aq, bk[4];
    aq = *(const s16x8*)(q + base + (long)(w * 16 + fr) * 512 + ks * 32 + fk);
#pragma unroll
    for (int j = 0; j < 4; j++)
      bk[j] = *(const s16x8*)&KVT[j * 16 + fr][ks * 32 + fk];
#pragma unroll
    for (int j = 0; j < 4; j++)
      acc2[j] = __builtin_amdgcn_mfma_f32_16x16x32_bf16(aq, bk[j], acc2[j], 0, 0, 0);
  }
  __syncthreads();
  const int colL = lane & 15, rb = (lane >> 4) * 4;
#pragma unroll
  for (int r = 0; r < 4; r++) {
    int nr = w * 16 + rb + r;
    float inv = dinv[nr];
#pragma unroll
    for (int j = 0; j < 4; j++) {
      long o = base + (long)nr * 512 + j * 16 + colL;
      attc[o] = f2bf(bf2f(attc[o]) + acc2[j][r] * inv);
    }
  }
}

// ============================================================================
extern "C" void kernel_launch(void* const* d_in, const int* in_sizes, int n_in,
                              void* d_out, int out_size, void* d_ws, size_t ws_size,
                              hipStream_t stream) {
  const float* X    = (const float*)d_in[0];
  const float* Z    = (const float*)d_in[1];
  const float* n1   = (const float*)d_in[2];
  const float* n2   = (const float*)d_in[3];
  const float* n3   = (const float*)d_in[4];
  const float* nz   = (const float*)d_in[5];
  const float* a_wq = (const float*)d_in[6];
  const float* a_wk = (const float*)d_in[7];
  const float* a_wv = (const float*)d_in[8];
  const float* a_wo = (const float*)d_in[9];
  const float* c_wq = (const float*)d_in[10];
  const float* c_wk = (const float*)d_in[11];
  const float* c_wv = (const float*)d_in[12];
  const float* c_wo = (const float*)d_in[13];
  const float* f_w1 = (const float*)d_in[14];
  const float* f_w2 = (const float*)d_in[15];
  const float* f_w3 = (const float*)d_in[16];
  float* out = (float*)d_out;
  (void)ws_size; (void)in_sizes; (void)n_in; (void)out_size;

  char* p = (char*)d_ws;
  size_t off = 0;
  auto take = [&](size_t bytes) -> char* {
    char* r = p + off;
    off += (bytes + 255) & ~(size_t)255;
    return r;
  };
  // ws buffers: weights ~10.5 MiB + 3 x 64 MiB = ~203 MiB total
  u16* w_aq = (u16*)take(512 * 512 * 2);
  u16* w_ak = (u16*)take(512 * 512 * 2);
  u16* w_av = (u16*)take(512 * 512 * 2);
  u16* w_ao = (u16*)take(512 * 512 * 2);
  u16* w_cq = (u16*)take(512 * 512 * 2);
  u16* w_ck = (u16*)take(512 * 512 * 2);
  u16* w_cv = (u16*)take(512 * 512 * 2);
  u16* w_co = (u16*)take(512 * 512 * 2);
  u16* w_f1 = (u16*)take(2048 * 512 * 2);
  u16* w_f3 = (u16*)take(2048 * 512 * 2);
  u16* w_f2 = (u16*)take(512 * 2048 * 2);
  u16* xn   = (u16*)take((size_t)65536 * 512 * 2);   // normed input; attc aliases
  u16* hbuf = (u16*)take((size_t)65536 * 512 * 2);   // bf16 residual h
  u16* qbuf = (u16*)take((size_t)65536 * 512 * 2);   // q; FFN hidden chunk aliases
  // d_out as scratch (128 MiB): k | v  (dead before phase 3 writes out)
  u16* kbuf = (u16*)d_out;
  u16* vbuf = (u16*)d_out + (size_t)65536 * 512;
  u16* attc = xn;     // alias: normed input dead once v-projection done
  u16* tslot = qbuf;  // FFN: [16384][2048] bf16 chunk = 64 MiB

  dim3 b256(256);
  dim3 gP(4, 512);     // N=512, M=65536  -> 2048 blocks
  dim3 gU(16, 128);    // N=2048, M=16384 -> 2048 blocks
  dim3 gD(4, 128);     // N=512, M=16384  -> 512 blocks

  // weight prep
  wprep<512, 512><<<64, b256, 0, stream>>>(a_wq, w_aq);
  wprep<512, 512><<<64, b256, 0, stream>>>(a_wk, w_ak);
  wprep<512, 512><<<64, b256, 0, stream>>>(a_wv, w_av);
  wprep<512, 512><<<64, b256, 0, stream>>>(a_wo, w_ao);
  wprep<512, 512><<<64, b256, 0, stream>>>(c_wq, w_cq);
  wprep<512, 512><<<64, b256, 0, stream>>>(c_wk, w_ck);
  wprep<512, 512><<<64, b256, 0, stream>>>(c_wv, w_cv);
  wprep<512, 512><<<64, b256, 0, stream>>>(c_wo, w_co);
  wprep<512, 2048><<<256, b256, 0, stream>>>(f_w1, w_f1);
  wprep<512, 2048><<<256, b256, 0, stream>>>(f_w3, w_f3);
  wprep<2048, 512><<<256, b256, 0, stream>>>(f_w2, w_f2);

  // ---------------- Phase 1: h = X + SelfAtt(norm1(X)) ----------------------
  rmsnorm_f32<<<16384, b256, 0, stream>>>(X, n1, xn);
  gemm2<512, EPI_PHI><<<gP, b256, 0, stream>>>(xn, w_aq, qbuf, nullptr, 512);
  gemm2<512, EPI_PHI><<<gP, b256, 0, stream>>>(xn, w_ak, kbuf, nullptr, 512);
  gemm2<512, EPI_BF16><<<gP, b256, 0, stream>>>(xn, w_av, vbuf, nullptr, 512);
  att_mode1<<<2048, b256, 0, stream>>>(qbuf, kbuf, vbuf, attc);
  att_mode2<<<8192, b256, 0, stream>>>(qbuf, kbuf, vbuf, attc);
  gemm2<512, EPI_RESX><<<gP, b256, 0, stream>>>(attc, w_ao, hbuf, X, 512);

  // ---------------- Phase 2: h += CrossAtt(norm3(h), normz(Z)) --------------
  rmsnorm_bf16<<<16384, b256, 0, stream>>>(hbuf, n3, xn);
  gemm2<512, EPI_PHI><<<gP, b256, 0, stream>>>(xn, w_cq, qbuf, nullptr, 512);
  rmsnorm_f32<<<16384, b256, 0, stream>>>(Z, nz, xn);
  gemm2<512, EPI_PHI><<<gP, b256, 0, stream>>>(xn, w_ck, kbuf, nullptr, 512);
  gemm2<512, EPI_BF16><<<gP, b256, 0, stream>>>(xn, w_cv, vbuf, nullptr, 512);
  att_mode1<<<2048, b256, 0, stream>>>(qbuf, kbuf, vbuf, attc);
  att_mode2<<<8192, b256, 0, stream>>>(qbuf, kbuf, vbuf, attc);
  gemm2<512, EPI_RESH><<<gP, b256, 0, stream>>>(attc, w_co, hbuf, hbuf, 512);

  // ---------------- Phase 3: out = h + SwiGLU(norm2(h)) ---------------------
  rmsnorm_bf16<<<16384, b256, 0, stream>>>(hbuf, n2, xn);
  const int CH = 16384;
  for (int c = 0; c < 4; c++) {
    const size_t ro = (size_t)c * CH * 512;
    const size_t rf = (size_t)c * CH * 2048;
    (void)rf;
    gemm2<512, EPI_BF16><<<gU, b256, 0, stream>>>(xn + ro * 4 / 4, w_f1, tslot, nullptr, 2048);
    gemm2<512, EPI_SILUMUL><<<gU, b256, 0, stream>>>(xn + ro, w_f3, tslot, tslot, 2048);
    gemm2<2048, EPI_OUTF><<<gD, b256, 0, stream>>>(tslot, w_f2, out + ro, hbuf + ro, 512);
  }
}

// Round 5
// 1564.599 us; speedup vs baseline: 1.2292x; 1.0957x over previous
//
#include <hip/hip_runtime.h>

typedef short s16x8 __attribute__((ext_vector_type(8)));
typedef float f32x4 __attribute__((ext_vector_type(4)));
typedef unsigned short u16;
typedef unsigned int u32;

__device__ __forceinline__ float bf2f(u16 u) {
  union { unsigned int i; float f; } v; v.i = ((unsigned int)u) << 16; return v.f;
}
__device__ __forceinline__ u16 f2bf(float f) {
  union { float f; unsigned int i; } v; v.f = f;
  unsigned int r = v.i + 0x7fffu + ((v.i >> 16) & 1u);
  return (u16)(r >> 16);
}

// async global->LDS, 16B per lane. LDS dest must be wave-uniform; HW adds lane*16.
__device__ __forceinline__ void gload16(const u16* g, u16* l) {
  __builtin_amdgcn_global_load_lds(
      (const __attribute__((address_space(1))) u32*)g,
      (__attribute__((address_space(3))) u32*)l, 16, 0, 0);
}

// ---------------- weight transpose + cast: in[K][N] f32 -> out[N][K] bf16 ----
template<int KDIM, int NDIM>
__launch_bounds__(256)
__global__ void wprep(const float* __restrict__ in, u16* __restrict__ out) {
  __shared__ float t[64][65];
  const int tid = threadIdx.x;
  const int nb = NDIM / 64;
  const int tk0 = (blockIdx.x / nb) * 64;
  const int tn0 = (blockIdx.x % nb) * 64;
#pragma unroll
  for (int i = 0; i < 16; i++) {
    int idx = i * 256 + tid;
    int r = idx >> 6, c = idx & 63;
    t[r][c] = in[(long)(tk0 + r) * NDIM + (tn0 + c)];
  }
  __syncthreads();
#pragma unroll
  for (int i = 0; i < 16; i++) {
    int idx = i * 256 + tid;
    int nn = idx >> 6, kk = idx & 63;
    out[(long)(tn0 + nn) * KDIM + (tk0 + kk)] = f2bf(t[kk][nn]);
  }
}

// ---------------- rmsnorm (f32 src) + cast to bf16 --------------------------
__launch_bounds__(256)
__global__ void rmsnorm_f32(const float* __restrict__ x, const float* __restrict__ w,
                            u16* __restrict__ out) {
  const long row = (long)blockIdx.x * 4 + (threadIdx.x >> 6);
  const int lane = threadIdx.x & 63;
  const float* xr = x + row * 512 + lane * 8;
  float4 v0 = *(const float4*)xr;
  float4 v1 = *(const float4*)(xr + 4);
  float ss = v0.x*v0.x + v0.y*v0.y + v0.z*v0.z + v0.w*v0.w
           + v1.x*v1.x + v1.y*v1.y + v1.z*v1.z + v1.w*v1.w;
#pragma unroll
  for (int o = 1; o < 64; o <<= 1) ss += __shfl_xor(ss, o);
  float sc = rsqrtf(ss * (1.0f / 512.0f) + 1e-6f);
  const float* wp = w + lane * 8;
  float4 w0 = *(const float4*)wp;
  float4 w1 = *(const float4*)(wp + 4);
  union { u16 u[8]; uint4 v; } o;
  o.u[0] = f2bf(v0.x * sc * w0.x);
  o.u[1] = f2bf(v0.y * sc * w0.y);
  o.u[2] = f2bf(v0.z * sc * w0.z);
  o.u[3] = f2bf(v0.w * sc * w0.w);
  o.u[4] = f2bf(v1.x * sc * w1.x);
  o.u[5] = f2bf(v1.y * sc * w1.y);
  o.u[6] = f2bf(v1.z * sc * w1.z);
  o.u[7] = f2bf(v1.w * sc * w1.w);
  *(uint4*)(out + row * 512 + lane * 8) = o.v;
}

// ---------------- rmsnorm (bf16 src) + cast to bf16 -------------------------
__launch_bounds__(256)
__global__ void rmsnorm_bf16(const u16* __restrict__ x, const float* __restrict__ w,
                             u16* __restrict__ out) {
  const long row = (long)blockIdx.x * 4 + (threadIdx.x >> 6);
  const int lane = threadIdx.x & 63;
  uint4 u = *(const uint4*)(x + row * 512 + lane * 8);
  const u16* us = (const u16*)&u;
  float f[8];
  float ss = 0.f;
#pragma unroll
  for (int j = 0; j < 8; j++) { f[j] = bf2f(us[j]); ss += f[j] * f[j]; }
#pragma unroll
  for (int o = 1; o < 64; o <<= 1) ss += __shfl_xor(ss, o);
  float sc = rsqrtf(ss * (1.0f / 512.0f) + 1e-6f);
  const float* wp = w + lane * 8;
  union { u16 u[8]; uint4 v; } o;
#pragma unroll
  for (int j = 0; j < 8; j++) o.u[j] = f2bf(f[j] * sc * wp[j]);
  *(uint4*)(out + row * 512 + lane * 8) = o.v;
}

// ---- 256x256 counted-vmcnt GEMM: C[M,Ns] = A[M,KD] @ Bt[Ns,KD]^T ------------
// 512 threads = 8 waves (2 M-waves x 4 N-waves), BK=64, double-buffered LDS
// (128 KiB), T2 XOR-swizzle (linear gload dest + pre-swizzled global source),
// T4 counted vmcnt(8) across raw s_barrier.
enum { EPI_BF16 = 0, EPI_PHI = 1, EPI_RESX = 2, EPI_RESH = 3, EPI_SILUMUL = 4, EPI_OUTF = 5 };

template<int KD, int EPI>
__launch_bounds__(512)
__global__ void gemm256(const u16* __restrict__ A, const u16* __restrict__ Bt,
                        void* __restrict__ Cout, const void* __restrict__ aux,
                        int Ns) {
  __shared__ u16 As[2][256][64];
  __shared__ u16 Bs[2][256][64];
  const int tid = threadIdx.x;
  const int lane = tid & 63;
  const int wid = tid >> 6;
  // bijective XCD swizzle (all grids have nwg % 8 == 0)
  const int gx = gridDim.x;
  int L = blockIdx.y * gx + blockIdx.x;
  const int cpx = (gx * gridDim.y) >> 3;
  L = (L & 7) * cpx + (L >> 3);
  const long m0 = (long)(L / gx) * 256;
  const long n0 = (long)(L % gx) * 256;

  const int wrbase = (wid >> 2) * 128;   // 2 M-waves: rows 0..127 / 128..255
  const int wcbase = (wid & 3) * 64;     // 4 N-waves: cols 0,64,128,192
  const int fr = lane & 15;
  const int frq = lane >> 4;             // 0..3

  // staging addresses: instr j in 0..3, this wave covers LDS bytes
  //   j*8192 + wid*1024 + lane*16  of the 32KB operand tile.
  // LDS(row, slot) holds global (row, slot ^ (row&7)); pre-swizzled source:
  const int rA0 = wid * 8 + (lane >> 3);                       // row for j=0
  const int sg8 = (((lane & 7) ^ ((lane >> 3) & 7))) * 8;      // source slot*8
  const u16* Ag = A + (m0 + rA0) * KD + sg8;
  const u16* Bg = Bt + (n0 + rA0) * KD + sg8;
  u16* Alds = &As[0][0][0] + wid * 512;   // + buf*16384 + j*4096
  u16* Blds = &Bs[0][0][0] + wid * 512;

  f32x4 acc[8][4] = {};

  auto STAGE = [&](int b, int kt) {
    const long k0 = (long)kt * 64;
#pragma unroll
    for (int j = 0; j < 4; j++) {
      gload16(Ag + (long)(j * 64) * KD + k0, Alds + b * 16384 + j * 4096);
      gload16(Bg + (long)(j * 64) * KD + k0, Blds + b * 16384 + j * 4096);
    }
  };
  auto COMPUTE = [&](int b) {
#pragma unroll
    for (int ks = 0; ks < 2; ks++) {
      const int slot = ((ks * 4 + frq) ^ (fr & 7)) * 8;   // swizzled 16B slot
      s16x8 af[8], bf[4];
#pragma unroll
      for (int i = 0; i < 8; i++) af[i] = *(const s16x8*)&As[b][wrbase + i * 16 + fr][slot];
#pragma unroll
      for (int j = 0; j < 4; j++) bf[j] = *(const s16x8*)&Bs[b][wcbase + j * 16 + fr][slot];
#pragma unroll
      for (int i = 0; i < 8; i++)
#pragma unroll
        for (int j = 0; j < 4; j++)
          acc[i][j] = __builtin_amdgcn_mfma_f32_16x16x32_bf16(af[i], bf[j], acc[i][j], 0, 0, 0);
    }
  };

  constexpr int NT = KD / 64;
  STAGE(0, 0);
#pragma unroll 1
  for (int t = 0; t < NT; ++t) {
    if (t + 1 < NT) {
      STAGE((t + 1) & 1, t + 1);                       // prefetch stays in flight
      asm volatile("s_waitcnt vmcnt(8)" ::: "memory"); // tile t complete, t+1 pending
    } else {
      asm volatile("s_waitcnt vmcnt(0)" ::: "memory");
    }
    __builtin_amdgcn_s_barrier();                      // tile t visible to all waves
    COMPUTE(t & 1);
    asm volatile("s_waitcnt lgkmcnt(0)" ::: "memory"); // all ds_reads of buf done
    __builtin_amdgcn_s_barrier();                      // safe to overwrite buf
  }

  const int col = lane & 15;
  const int rb = frq * 4;
#pragma unroll
  for (int i = 0; i < 8; i++) {
#pragma unroll
    for (int r = 0; r < 4; r++) {
      long m = m0 + wrbase + i * 16 + rb + r;
#pragma unroll
      for (int j = 0; j < 4; j++) {
        long n = n0 + wcbase + j * 16 + col;
        long off = m * Ns + n;
        float v = acc[i][j][r];
        if constexpr (EPI == EPI_BF16) {
          ((u16*)Cout)[off] = f2bf(v);
        } else if constexpr (EPI == EPI_PHI) {
          float p = v > 0.f ? v + 1.f : __expf(v);
          ((u16*)Cout)[off] = f2bf(p);
        } else if constexpr (EPI == EPI_RESX) {
          ((u16*)Cout)[off] = f2bf(((const float*)aux)[off] + v);
        } else if constexpr (EPI == EPI_RESH) {
          ((u16*)Cout)[off] = f2bf(bf2f(((const u16*)aux)[off]) + v);
        } else if constexpr (EPI == EPI_SILUMUL) {
          float t2 = bf2f(((const u16*)aux)[off]);
          float s = t2 / (1.f + __expf(-t2));
          ((u16*)Cout)[off] = f2bf(s * v);
        } else {  // EPI_OUTF: out f32 = h(bf16) + v
          ((float*)Cout)[off] = bf2f(((const u16*)aux)[off]) + v;
        }
      }
    }
  }
}

// ---------------- fused attention, mode 1 (time): one WG per (b,n,h) --------
__launch_bounds__(256)
__global__ void att_mode1(const u16* __restrict__ q, const u16* __restrict__ k,
                          const u16* __restrict__ v, u16* __restrict__ attc) {
  __shared__ u16 Ks[128][72];
  __shared__ u16 Vs[128][72];
  __shared__ u16 KVT[64][72];
  __shared__ float ksump[4][64];
  __shared__ float ksum_s[64];
  __shared__ float dinv[256];
  const int tid = threadIdx.x;
  const int lane = tid & 63;
  const int w = tid >> 6;
  const int bnh = blockIdx.x;          // ((b*64+n)*8+h)
  const int h = bnh & 7;
  const int bn = bnh >> 3;
  const int n = bn & 63;
  const int b = bn >> 6;
  const long base = ((long)b * 16384 + n) * 512 + h * 64;   // + t*32768
  const int fr = lane & 15;
  const int fk = (lane >> 4) * 8;
  const int sdk = tid & 63, sqq = tid >> 6;

  f32x4 acc[4] = {};
  float ks_acc = 0.f;

  for (int half = 0; half < 2; half++) {
    __syncthreads();
#pragma unroll
    for (int rep = 0; rep < 4; rep++) {
      int idx = rep * 256 + tid;
      int tl = idx >> 3, c8 = idx & 7;
      long go = base + (long)(half * 128 + tl) * 32768 + c8 * 8;
      *(uint4*)&Ks[tl][c8 * 8] = *(const uint4*)(k + go);
      *(uint4*)&Vs[tl][c8 * 8] = *(const uint4*)(v + go);
    }
    __syncthreads();
#pragma unroll
    for (int i = 0; i < 32; i++) ks_acc += bf2f(Ks[sqq * 32 + i][sdk]);
#pragma unroll
    for (int ks = 0; ks < 4; ks++) {
      s16x8 af, bfr[4];
#pragma unroll
      for (int e = 0; e < 8; e++) af[e] = (short)Vs[ks * 32 + fk + e][w * 16 + fr];
#pragma unroll
      for (int j = 0; j < 4; j++)
#pragma unroll
        for (int e = 0; e < 8; e++) bfr[j][e] = (short)Ks[ks * 32 + fk + e][j * 16 + fr];
#pragma unroll
      for (int j = 0; j < 4; j++)
        acc[j] = __builtin_amdgcn_mfma_f32_16x16x32_bf16(af, bfr[j], acc[j], 0, 0, 0);
    }
  }
  ksump[sqq][sdk] = ks_acc;
  __syncthreads();
  {
    const int colL = lane & 15, rb = (lane >> 4) * 4;
#pragma unroll
    for (int j = 0; j < 4; j++)
#pragma unroll
      for (int r = 0; r < 4; r++)
        KVT[w * 16 + rb + r][j * 16 + colL] = f2bf(acc[j][r]);
  }
  if (tid < 64) ksum_s[tid] = ksump[0][tid] + ksump[1][tid] + ksump[2][tid] + ksump[3][tid];
  __syncthreads();
  {
    const u16* qp = q + base + (long)tid * 32768;
    float d = 0.f;
#pragma unroll
    for (int c8 = 0; c8 < 8; c8++) {
      uint4 u = ((const uint4*)qp)[c8];
      const u16* us = (const u16*)&u;
#pragma unroll
      for (int e = 0; e < 8; e++) d += bf2f(us[e]) * ksum_s[c8 * 8 + e];
    }
    dinv[tid] = 0.5f / (d + 1e-6f);
  }
  f32x4 acc2[4][4] = {};
#pragma unroll
  for (int ks = 0; ks < 2; ks++) {
    s16x8 aq[4], bk[4];
#pragma unroll
    for (int i = 0; i < 4; i++)
      aq[i] = *(const s16x8*)(q + base + (long)(w * 64 + i * 16 + fr) * 32768 + ks * 32 + fk);
#pragma unroll
    for (int j = 0; j < 4; j++)
      bk[j] = *(const s16x8*)&KVT[j * 16 + fr][ks * 32 + fk];
#pragma unroll
    for (int i = 0; i < 4; i++)
#pragma unroll
      for (int j = 0; j < 4; j++)
        acc2[i][j] = __builtin_amdgcn_mfma_f32_16x16x32_bf16(aq[i], bk[j], acc2[i][j], 0, 0, 0);
  }
  __syncthreads();
  const int colL = lane & 15, rb = (lane >> 4) * 4;
#pragma unroll
  for (int i = 0; i < 4; i++)
#pragma unroll
    for (int r = 0; r < 4; r++) {
      int t = w * 64 + i * 16 + rb + r;
      float inv = dinv[t];
#pragma unroll
      for (int j = 0; j < 4; j++)
        attc[base + (long)t * 32768 + j * 16 + colL] = f2bf(acc2[i][j][r] * inv);
    }
}

// ---------------- fused attention, mode 2 (entities): one WG per (b,t,h) ----
__launch_bounds__(256)
__global__ void att_mode2(const u16* __restrict__ q, const u16* __restrict__ k,
                          const u16* __restrict__ v, u16* __restrict__ attc) {
  __shared__ u16 Ks[64][72];
  __shared__ u16 Vs[64][72];
  __shared__ u16 KVT[64][72];
  __shared__ float ksump[4][64];
  __shared__ float ksum_s[64];
  __shared__ float dinv[64];
  const int tid = threadIdx.x;
  const int lane = tid & 63;
  const int w = tid >> 6;
  const int bth = blockIdx.x;          // ((b*256+t)*8+h)
  const int h = bth & 7;
  const long bt = bth >> 3;
  const long base = bt * 32768 + h * 64;   // + n*512
  const int fr = lane & 15;
  const int fk = (lane >> 4) * 8;
  const int sdk = tid & 63, sqq = tid >> 6;

#pragma unroll
  for (int rep = 0; rep < 2; rep++) {
    int idx = rep * 256 + tid;
    int nl = idx >> 3, c8 = idx & 7;
    long go = base + (long)nl * 512 + c8 * 8;
    *(uint4*)&Ks[nl][c8 * 8] = *(const uint4*)(k + go);
    *(uint4*)&Vs[nl][c8 * 8] = *(const uint4*)(v + go);
  }
  __syncthreads();
  {
    float s = 0.f;
#pragma unroll
    for (int i = 0; i < 16; i++) s += bf2f(Ks[sqq * 16 + i][sdk]);
    ksump[sqq][sdk] = s;
  }
  f32x4 acc[4] = {};
#pragma unroll
  for (int ks = 0; ks < 2; ks++) {
    s16x8 af, bfr[4];
#pragma unroll
    for (int e = 0; e < 8; e++) af[e] = (short)Vs[ks * 32 + fk + e][w * 16 + fr];
#pragma unroll
    for (int j = 0; j < 4; j++)
#pragma unroll
      for (int e = 0; e < 8; e++) bfr[j][e] = (short)Ks[ks * 32 + fk + e][j * 16 + fr];
#pragma unroll
    for (int j = 0; j < 4; j++)
      acc[j] = __builtin_amdgcn_mfma_f32_16x16x32_bf16(af, bfr[j], acc[j], 0, 0, 0);
  }
  __syncthreads();
  {
    const int colL = lane & 15, rb = (lane >> 4) * 4;
#pragma unroll
    for (int j = 0; j < 4; j++)
#pragma unroll
      for (int r = 0; r < 4; r++)
        KVT[w * 16 + rb + r][j * 16 + colL] = f2bf(acc[j][r]);
  }
  if (tid < 64) ksum_s[tid] = ksump[0][tid] + ksump[1][tid] + ksump[2][tid] + ksump[3][tid];
  __syncthreads();
  if (tid < 64) {
    const u16* qp = q + base + (long)tid * 512;
    float d = 0.f;
#pragma unroll
    for (int c8 = 0; c8 < 8; c8++) {
      uint4 u = ((const uint4*)qp)[c8];
      const u16* us = (const u16*)&u;
#pragma unroll
      for (int e = 0; e < 8; e++) d += bf2f(us[e]) * ksum_s[c8 * 8 + e];
    }
    dinv[tid] = 0.5f / (d + 1e-6f);
  }
  f32x4 acc2[4] = {};
#pragma unroll
  for (int ks = 0; ks < 2; ks++) {
    s16x8 aq, bk[4];
    aq = *(const s16x8*)(q + base + (long)(w * 16 + fr) * 512 + ks * 32 + fk);
#pragma unroll
    for (int j = 0; j < 4; j++)
      bk[j] = *(const s16x8*)&KVT[j * 16 + fr][ks * 32 + fk];
#pragma unroll
    for (int j = 0; j < 4; j++)
      acc2[j] = __builtin_amdgcn_mfma_f32_16x16x32_bf16(aq, bk[j], acc2[j], 0, 0, 0);
  }
  __syncthreads();
  const int colL = lane & 15, rb = (lane >> 4) * 4;
#pragma unroll
  for (int r = 0; r < 4; r++) {
    int nr = w * 16 + rb + r;
    float inv = dinv[nr];
#pragma unroll
    for (int j = 0; j < 4; j++) {
      long o = base + (long)nr * 512 + j * 16 + colL;
      attc[o] = f2bf(bf2f(attc[o]) + acc2[j][r] * inv);
    }
  }
}

// ============================================================================
extern "C" void kernel_launch(void* const* d_in, const int* in_sizes, int n_in,
                              void* d_out, int out_size, void* d_ws, size_t ws_size,
                              hipStream_t stream) {
  const float* X    = (const float*)d_in[0];
  const float* Z    = (const float*)d_in[1];
  const float* n1   = (const float*)d_in[2];
  const float* n2   = (const float*)d_in[3];
  const float* n3   = (const float*)d_in[4];
  const float* nz   = (const float*)d_in[5];
  const float* a_wq = (const float*)d_in[6];
  const float* a_wk = (const float*)d_in[7];
  const float* a_wv = (const float*)d_in[8];
  const float* a_wo = (const float*)d_in[9];
  const float* c_wq = (const float*)d_in[10];
  const float* c_wk = (const float*)d_in[11];
  const float* c_wv = (const float*)d_in[12];
  const float* c_wo = (const float*)d_in[13];
  const float* f_w1 = (const float*)d_in[14];
  const float* f_w2 = (const float*)d_in[15];
  const float* f_w3 = (const float*)d_in[16];
  float* out = (float*)d_out;
  (void)ws_size; (void)in_sizes; (void)n_in; (void)out_size;

  char* p = (char*)d_ws;
  size_t off = 0;
  auto take = [&](size_t bytes) -> char* {
    char* r = p + off;
    off += (bytes + 255) & ~(size_t)255;
    return r;
  };
  // ws buffers: weights ~10.5 MiB + 3 x 64 MiB = ~203 MiB total
  u16* w_aq = (u16*)take(512 * 512 * 2);
  u16* w_ak = (u16*)take(512 * 512 * 2);
  u16* w_av = (u16*)take(512 * 512 * 2);
  u16* w_ao = (u16*)take(512 * 512 * 2);
  u16* w_cq = (u16*)take(512 * 512 * 2);
  u16* w_ck = (u16*)take(512 * 512 * 2);
  u16* w_cv = (u16*)take(512 * 512 * 2);
  u16* w_co = (u16*)take(512 * 512 * 2);
  u16* w_f1 = (u16*)take(2048 * 512 * 2);
  u16* w_f3 = (u16*)take(2048 * 512 * 2);
  u16* w_f2 = (u16*)take(512 * 2048 * 2);
  u16* xn   = (u16*)take((size_t)65536 * 512 * 2);   // normed input; attc aliases
  u16* hbuf = (u16*)take((size_t)65536 * 512 * 2);   // bf16 residual h
  u16* qbuf = (u16*)take((size_t)65536 * 512 * 2);   // q; FFN hidden chunk aliases
  // d_out as scratch (128 MiB): k | v  (dead before phase 3 writes out)
  u16* kbuf = (u16*)d_out;
  u16* vbuf = (u16*)d_out + (size_t)65536 * 512;
  u16* attc = xn;     // alias: normed input dead once v-projection done
  u16* tslot = qbuf;  // FFN: [16384][2048] bf16 chunk = 64 MiB

  dim3 b256(256);
  dim3 b512(512);
  dim3 gP(2, 256);     // N=512, M=65536  -> 512 blocks (256^2 tiles)
  dim3 gU(8, 64);      // N=2048, M=16384 -> 512 blocks
  dim3 gD(2, 64);      // N=512, M=16384  -> 128 blocks

  // weight prep
  wprep<512, 512><<<64, b256, 0, stream>>>(a_wq, w_aq);
  wprep<512, 512><<<64, b256, 0, stream>>>(a_wk, w_ak);
  wprep<512, 512><<<64, b256, 0, stream>>>(a_wv, w_av);
  wprep<512, 512><<<64, b256, 0, stream>>>(a_wo, w_ao);
  wprep<512, 512><<<64, b256, 0, stream>>>(c_wq, w_cq);
  wprep<512, 512><<<64, b256, 0, stream>>>(c_wk, w_ck);
  wprep<512, 512><<<64, b256, 0, stream>>>(c_wv, w_cv);
  wprep<512, 512><<<64, b256, 0, stream>>>(c_wo, w_co);
  wprep<512, 2048><<<256, b256, 0, stream>>>(f_w1, w_f1);
  wprep<512, 2048><<<256, b256, 0, stream>>>(f_w3, w_f3);
  wprep<2048, 512><<<256, b256, 0, stream>>>(f_w2, w_f2);

  // ---------------- Phase 1: h = X + SelfAtt(norm1(X)) ----------------------
  rmsnorm_f32<<<16384, b256, 0, stream>>>(X, n1, xn);
  gemm256<512, EPI_PHI><<<gP, b512, 0, stream>>>(xn, w_aq, qbuf, nullptr, 512);
  gemm256<512, EPI_PHI><<<gP, b512, 0, stream>>>(xn, w_ak, kbuf, nullptr, 512);
  gemm256<512, EPI_BF16><<<gP, b512, 0, stream>>>(xn, w_av, vbuf, nullptr, 512);
  att_mode1<<<2048, b256, 0, stream>>>(qbuf, kbuf, vbuf, attc);
  att_mode2<<<8192, b256, 0, stream>>>(qbuf, kbuf, vbuf, attc);
  gemm256<512, EPI_RESX><<<gP, b512, 0, stream>>>(attc, w_ao, hbuf, X, 512);

  // ---------------- Phase 2: h += CrossAtt(norm3(h), normz(Z)) --------------
  rmsnorm_bf16<<<16384, b256, 0, stream>>>(hbuf, n3, xn);
  gemm256<512, EPI_PHI><<<gP, b512, 0, stream>>>(xn, w_cq, qbuf, nullptr, 512);
  rmsnorm_f32<<<16384, b256, 0, stream>>>(Z, nz, xn);
  gemm256<512, EPI_PHI><<<gP, b512, 0, stream>>>(xn, w_ck, kbuf, nullptr, 512);
  gemm256<512, EPI_BF16><<<gP, b512, 0, stream>>>(xn, w_cv, vbuf, nullptr, 512);
  att_mode1<<<2048, b256, 0, stream>>>(qbuf, kbuf, vbuf, attc);
  att_mode2<<<8192, b256, 0, stream>>>(qbuf, kbuf, vbuf, attc);
  gemm256<512, EPI_RESH><<<gP, b512, 0, stream>>>(attc, w_co, hbuf, hbuf, 512);

  // ---------------- Phase 3: out = h + SwiGLU(norm2(h)) ---------------------
  rmsnorm_bf16<<<16384, b256, 0, stream>>>(hbuf, n2, xn);
  const int CH = 16384;
  for (int c = 0; c < 4; c++) {
    const size_t ro = (size_t)c * CH * 512;
    gemm256<512, EPI_BF16><<<gU, b512, 0, stream>>>(xn + ro, w_f1, tslot, nullptr, 2048);
    gemm256<512, EPI_SILUMUL><<<gU, b512, 0, stream>>>(xn + ro, w_f3, tslot, tslot, 2048);
    gemm256<2048, EPI_OUTF><<<gD, b512, 0, stream>>>(tslot, w_f2, out + ro, hbuf + ro, 512);
  }
}

// Round 6
// 1498.082 us; speedup vs baseline: 1.2838x; 1.0444x over previous
//
#include <hip/hip_runtime.h>

typedef short s16x8 __attribute__((ext_vector_type(8)));
typedef float f32x4 __attribute__((ext_vector_type(4)));
typedef unsigned short u16;
typedef unsigned int u32;

__device__ __forceinline__ float bf2f(u16 u) {
  union { unsigned int i; float f; } v; v.i = ((unsigned int)u) << 16; return v.f;
}
__device__ __forceinline__ u16 f2bf(float f) {
  union { float f; unsigned int i; } v; v.f = f;
  unsigned int r = v.i + 0x7fffu + ((v.i >> 16) & 1u);
  return (u16)(r >> 16);
}

// async global->LDS, 16B per lane. LDS dest must be wave-uniform; HW adds lane*16.
__device__ __forceinline__ void gload16(const u16* g, u16* l) {
  __builtin_amdgcn_global_load_lds(
      (const __attribute__((address_space(1))) u32*)g,
      (__attribute__((address_space(3))) u32*)l, 16, 0, 0);
}

// ---------------- weight transpose + cast: in[K][N] f32 -> out[N][K] bf16 ----
template<int KDIM, int NDIM>
__launch_bounds__(256)
__global__ void wprep(const float* __restrict__ in, u16* __restrict__ out) {
  __shared__ float t[64][65];
  const int tid = threadIdx.x;
  const int nb = NDIM / 64;
  const int tk0 = (blockIdx.x / nb) * 64;
  const int tn0 = (blockIdx.x % nb) * 64;
#pragma unroll
  for (int i = 0; i < 16; i++) {
    int idx = i * 256 + tid;
    int r = idx >> 6, c = idx & 63;
    t[r][c] = in[(long)(tk0 + r) * NDIM + (tn0 + c)];
  }
  __syncthreads();
#pragma unroll
  for (int i = 0; i < 16; i++) {
    int idx = i * 256 + tid;
    int nn = idx >> 6, kk = idx & 63;
    out[(long)(tn0 + nn) * KDIM + (tk0 + kk)] = f2bf(t[kk][nn]);
  }
}

// ---------------- rmsnorm (f32 src) + cast to bf16 --------------------------
__launch_bounds__(256)
__global__ void rmsnorm_f32(const float* __restrict__ x, const float* __restrict__ w,
                            u16* __restrict__ out) {
  const long row = (long)blockIdx.x * 4 + (threadIdx.x >> 6);
  const int lane = threadIdx.x & 63;
  const float* xr = x + row * 512 + lane * 8;
  float4 v0 = *(const float4*)xr;
  float4 v1 = *(const float4*)(xr + 4);
  float ss = v0.x*v0.x + v0.y*v0.y + v0.z*v0.z + v0.w*v0.w
           + v1.x*v1.x + v1.y*v1.y + v1.z*v1.z + v1.w*v1.w;
#pragma unroll
  for (int o = 1; o < 64; o <<= 1) ss += __shfl_xor(ss, o);
  float sc = rsqrtf(ss * (1.0f / 512.0f) + 1e-6f);
  const float* wp = w + lane * 8;
  float4 w0 = *(const float4*)wp;
  float4 w1 = *(const float4*)(wp + 4);
  union { u16 u[8]; uint4 v; } o;
  o.u[0] = f2bf(v0.x * sc * w0.x);
  o.u[1] = f2bf(v0.y * sc * w0.y);
  o.u[2] = f2bf(v0.z * sc * w0.z);
  o.u[3] = f2bf(v0.w * sc * w0.w);
  o.u[4] = f2bf(v1.x * sc * w1.x);
  o.u[5] = f2bf(v1.y * sc * w1.y);
  o.u[6] = f2bf(v1.z * sc * w1.z);
  o.u[7] = f2bf(v1.w * sc * w1.w);
  *(uint4*)(out + row * 512 + lane * 8) = o.v;
}

// ---------------- rmsnorm (bf16 src) + cast to bf16 -------------------------
__launch_bounds__(256)
__global__ void rmsnorm_bf16(const u16* __restrict__ x, const float* __restrict__ w,
                             u16* __restrict__ out) {
  const long row = (long)blockIdx.x * 4 + (threadIdx.x >> 6);
  const int lane = threadIdx.x & 63;
  uint4 u = *(const uint4*)(x + row * 512 + lane * 8);
  const u16* us = (const u16*)&u;
  float f[8];
  float ss = 0.f;
#pragma unroll
  for (int j = 0; j < 8; j++) { f[j] = bf2f(us[j]); ss += f[j] * f[j]; }
#pragma unroll
  for (int o = 1; o < 64; o <<= 1) ss += __shfl_xor(ss, o);
  float sc = rsqrtf(ss * (1.0f / 512.0f) + 1e-6f);
  const float* wp = w + lane * 8;
  union { u16 u[8]; uint4 v; } o;
#pragma unroll
  for (int j = 0; j < 8; j++) o.u[j] = f2bf(f[j] * sc * wp[j]);
  *(uint4*)(out + row * 512 + lane * 8) = o.v;
}

// ---- 128x128 dbuf counted-vmcnt GEMM: C[M,Ns] = A[M,KD] @ Bt[Ns,KD]^T -------
// 256 threads = 4 waves (2M x 2N), BK=64, double-buffered LDS (64 KiB ->
// 2 blocks/CU for cross-block barrier-stall overlap), T2 XOR swizzle
// (linear gload dest + pre-swizzled global source), counted vmcnt(8).
enum { EPI_BF16 = 0, EPI_PHI = 1, EPI_RESX = 2, EPI_RESH = 3, EPI_SILUMUL = 4,
       EPI_OUTF = 5, EPI_QKV = 6, EPI_KV = 7 };

template<int KD, int EPI>
__launch_bounds__(256)
__global__ void gemm128(const u16* __restrict__ A, const u16* __restrict__ Bt,
                        void* __restrict__ C0, void* __restrict__ C1,
                        void* __restrict__ C2, const void* __restrict__ aux,
                        int Ns) {
  __shared__ u16 As[2][128][64];
  __shared__ u16 Bs[2][128][64];
  const int tid = threadIdx.x;
  const int lane = tid & 63;
  const int wv = tid >> 6;
  // bijective XCD swizzle (all grids have nwg % 8 == 0)
  const int gx = gridDim.x;
  int L = blockIdx.y * gx + blockIdx.x;
  const int cpx = (gx * gridDim.y) >> 3;
  L = (L & 7) * cpx + (L >> 3);
  const long m0 = (long)(L / gx) * 128;
  const int nb = L % gx;
  const long n0 = (long)nb * 128;

  const int wr = (wv >> 1) * 64;   // 2 M-waves
  const int wc = (wv & 1) * 64;    // 2 N-waves
  const int fr = lane & 15;
  const int frq = lane >> 4;

  // staging: wave wv, instr j covers LDS rows [wv*32+j*8, +8) x 64 K-elems.
  // LDS(row, slot16) holds global(row, slot16 ^ (row&7)); pre-swizzled source.
  const int r0 = wv * 32 + (lane >> 3);
  const int sg8 = ((lane & 7) ^ ((lane >> 3) & 7)) * 8;
  const u16* Ag = A + (m0 + r0) * KD + sg8;
  const u16* Bg = Bt + (n0 + r0) * KD + sg8;
  u16* Alds = &As[0][0][0] + wv * 2048;   // + buf*8192 + j*512  (u16 units)
  u16* Blds = &Bs[0][0][0] + wv * 2048;

  f32x4 acc[4][4] = {};

  auto STAGE = [&](int b, int kt) {
    const long k0 = (long)kt * 64;
#pragma unroll
    for (int j = 0; j < 4; j++) {
      gload16(Ag + (long)(j * 8) * KD + k0, Alds + b * 8192 + j * 512);
      gload16(Bg + (long)(j * 8) * KD + k0, Blds + b * 8192 + j * 512);
    }
  };
  auto COMPUTE = [&](int b) {
#pragma unroll
    for (int ks = 0; ks < 2; ks++) {
      const int slot = ((ks * 4 + frq) ^ (fr & 7)) * 8;   // swizzled 16B slot
      s16x8 af[4], bf[4];
#pragma unroll
      for (int i = 0; i < 4; i++) af[i] = *(const s16x8*)&As[b][wr + i * 16 + fr][slot];
#pragma unroll
      for (int j = 0; j < 4; j++) bf[j] = *(const s16x8*)&Bs[b][wc + j * 16 + fr][slot];
#pragma unroll
      for (int i = 0; i < 4; i++)
#pragma unroll
        for (int j = 0; j < 4; j++)
          acc[i][j] = __builtin_amdgcn_mfma_f32_16x16x32_bf16(af[i], bf[j], acc[i][j], 0, 0, 0);
    }
  };

  constexpr int NT = KD / 64;
  STAGE(0, 0);
#pragma unroll 1
  for (int t = 0; t < NT; ++t) {
    if (t + 1 < NT) {
      STAGE((t + 1) & 1, t + 1);                       // prefetch stays in flight
      asm volatile("s_waitcnt vmcnt(8)" ::: "memory"); // tile t complete, t+1 pending
    } else {
      asm volatile("s_waitcnt vmcnt(0)" ::: "memory");
    }
    __builtin_amdgcn_s_barrier();                      // tile t visible to all waves
    COMPUTE(t & 1);
    asm volatile("s_waitcnt lgkmcnt(0)" ::: "memory"); // all ds_reads of buf done
    __builtin_amdgcn_s_barrier();                      // safe to overwrite buf
  }

  const int col = lane & 15;
  const int rb = frq * 4;
#pragma unroll
  for (int i = 0; i < 4; i++) {
#pragma unroll
    for (int r = 0; r < 4; r++) {
      long m = m0 + wr + i * 16 + rb + r;
#pragma unroll
      for (int j = 0; j < 4; j++) {
        long nlocal = wc + j * 16 + col;
        float v = acc[i][j][r];
        if constexpr (EPI == EPI_QKV) {
          // Ns=1536 segmented: n-tiles 0-3 -> q (phi), 4-7 -> k (phi), 8-11 -> v
          int seg = nb >> 2;
          long off = m * 512 + ((n0 + nlocal) & 511);
          u16* P = (u16*)(seg == 0 ? C0 : (seg == 1 ? C1 : C2));
          float p = (seg < 2) ? (v > 0.f ? v + 1.f : __expf(v)) : v;
          P[off] = f2bf(p);
        } else if constexpr (EPI == EPI_KV) {
          // Ns=1024 segmented: n-tiles 0-3 -> k (phi), 4-7 -> v
          int seg = nb >> 2;
          long off = m * 512 + ((n0 + nlocal) & 511);
          u16* P = (u16*)(seg == 0 ? C0 : C1);
          float p = (seg == 0) ? (v > 0.f ? v + 1.f : __expf(v)) : v;
          P[off] = f2bf(p);
        } else {
          long off = m * Ns + (n0 + nlocal);
          if constexpr (EPI == EPI_BF16) {
            ((u16*)C0)[off] = f2bf(v);
          } else if constexpr (EPI == EPI_PHI) {
            float p = v > 0.f ? v + 1.f : __expf(v);
            ((u16*)C0)[off] = f2bf(p);
          } else if constexpr (EPI == EPI_RESX) {
            ((u16*)C0)[off] = f2bf(((const float*)aux)[off] + v);
          } else if constexpr (EPI == EPI_RESH) {
            ((u16*)C0)[off] = f2bf(bf2f(((const u16*)aux)[off]) + v);
          } else if constexpr (EPI == EPI_SILUMUL) {
            float t2 = bf2f(((const u16*)aux)[off]);
            float s = t2 / (1.f + __expf(-t2));
            ((u16*)C0)[off] = f2bf(s * v);
          } else {  // EPI_OUTF: out f32 = h(bf16) + v
            ((float*)C0)[off] = bf2f(((const u16*)aux)[off]) + v;
          }
        }
      }
    }
  }
}

// ---------------- fused attention, mode 1 (time): one WG per (b,n,h) --------
__launch_bounds__(256)
__global__ void att_mode1(const u16* __restrict__ q, const u16* __restrict__ k,
                          const u16* __restrict__ v, u16* __restrict__ attc) {
  __shared__ u16 Ks[128][72];
  __shared__ u16 Vs[128][72];
  __shared__ u16 KVT[64][72];
  __shared__ float ksump[4][64];
  __shared__ float ksum_s[64];
  __shared__ float dinv[256];
  const int tid = threadIdx.x;
  const int lane = tid & 63;
  const int w = tid >> 6;
  const int bnh = blockIdx.x;          // ((b*64+n)*8+h)
  const int h = bnh & 7;
  const int bn = bnh >> 3;
  const int n = bn & 63;
  const int b = bn >> 6;
  const long base = ((long)b * 16384 + n) * 512 + h * 64;   // + t*32768
  const int fr = lane & 15;
  const int fk = (lane >> 4) * 8;
  const int sdk = tid & 63, sqq = tid >> 6;

  f32x4 acc[4] = {};
  float ks_acc = 0.f;

  for (int half = 0; half < 2; half++) {
    __syncthreads();
#pragma unroll
    for (int rep = 0; rep < 4; rep++) {
      int idx = rep * 256 + tid;
      int tl = idx >> 3, c8 = idx & 7;
      long go = base + (long)(half * 128 + tl) * 32768 + c8 * 8;
      *(uint4*)&Ks[tl][c8 * 8] = *(const uint4*)(k + go);
      *(uint4*)&Vs[tl][c8 * 8] = *(const uint4*)(v + go);
    }
    __syncthreads();
#pragma unroll
    for (int i = 0; i < 32; i++) ks_acc += bf2f(Ks[sqq * 32 + i][sdk]);
#pragma unroll
    for (int ks = 0; ks < 4; ks++) {
      s16x8 af, bfr[4];
#pragma unroll
      for (int e = 0; e < 8; e++) af[e] = (short)Vs[ks * 32 + fk + e][w * 16 + fr];
#pragma unroll
      for (int j = 0; j < 4; j++)
#pragma unroll
        for (int e = 0; e < 8; e++) bfr[j][e] = (short)Ks[ks * 32 + fk + e][j * 16 + fr];
#pragma unroll
      for (int j = 0; j < 4; j++)
        acc[j] = __builtin_amdgcn_mfma_f32_16x16x32_bf16(af, bfr[j], acc[j], 0, 0, 0);
    }
  }
  ksump[sqq][sdk] = ks_acc;
  __syncthreads();
  {
    const int colL = lane & 15, rb = (lane >> 4) * 4;
#pragma unroll
    for (int j = 0; j < 4; j++)
#pragma unroll
      for (int r = 0; r < 4; r++)
        KVT[w * 16 + rb + r][j * 16 + colL] = f2bf(acc[j][r]);
  }
  if (tid < 64) ksum_s[tid] = ksump[0][tid] + ksump[1][tid] + ksump[2][tid] + ksump[3][tid];
  __syncthreads();
  {
    const u16* qp = q + base + (long)tid * 32768;
    float d = 0.f;
#pragma unroll
    for (int c8 = 0; c8 < 8; c8++) {
      uint4 u = ((const uint4*)qp)[c8];
      const u16* us = (const u16*)&u;
#pragma unroll
      for (int e = 0; e < 8; e++) d += bf2f(us[e]) * ksum_s[c8 * 8 + e];
    }
    dinv[tid] = 0.5f / (d + 1e-6f);
  }
  f32x4 acc2[4][4] = {};
#pragma unroll
  for (int ks = 0; ks < 2; ks++) {
    s16x8 aq[4], bk[4];
#pragma unroll
    for (int i = 0; i < 4; i++)
      aq[i] = *(const s16x8*)(q + base + (long)(w * 64 + i * 16 + fr) * 32768 + ks * 32 + fk);
#pragma unroll
    for (int j = 0; j < 4; j++)
      bk[j] = *(const s16x8*)&KVT[j * 16 + fr][ks * 32 + fk];
#pragma unroll
    for (int i = 0; i < 4; i++)
#pragma unroll
      for (int j = 0; j < 4; j++)
        acc2[i][j] = __builtin_amdgcn_mfma_f32_16x16x32_bf16(aq[i], bk[j], acc2[i][j], 0, 0, 0);
  }
  __syncthreads();
  const int colL = lane & 15, rb = (lane >> 4) * 4;
#pragma unroll
  for (int i = 0; i < 4; i++)
#pragma unroll
    for (int r = 0; r < 4; r++) {
      int t = w * 64 + i * 16 + rb + r;
      float inv = dinv[t];
#pragma unroll
      for (int j = 0; j < 4; j++)
        attc[base + (long)t * 32768 + j * 16 + colL] = f2bf(acc2[i][j][r] * inv);
    }
}

// ---------------- fused attention, mode 2 (entities): one WG per (b,t,h) ----
__launch_bounds__(256)
__global__ void att_mode2(const u16* __restrict__ q, const u16* __restrict__ k,
                          const u16* __restrict__ v, u16* __restrict__ attc) {
  __shared__ u16 Ks[64][72];
  __shared__ u16 Vs[64][72];
  __shared__ u16 KVT[64][72];
  __shared__ float ksump[4][64];
  __shared__ float ksum_s[64];
  __shared__ float dinv[64];
  const int tid = threadIdx.x;
  const int lane = tid & 63;
  const int w = tid >> 6;
  const int bth = blockIdx.x;          // ((b*256+t)*8+h)
  const int h = bth & 7;
  const long bt = bth >> 3;
  const long base = bt * 32768 + h * 64;   // + n*512
  const int fr = lane & 15;
  const int fk = (lane >> 4) * 8;
  const int sdk = tid & 63, sqq = tid >> 6;

#pragma unroll
  for (int rep = 0; rep < 2; rep++) {
    int idx = rep * 256 + tid;
    int nl = idx >> 3, c8 = idx & 7;
    long go = base + (long)nl * 512 + c8 * 8;
    *(uint4*)&Ks[nl][c8 * 8] = *(const uint4*)(k + go);
    *(uint4*)&Vs[nl][c8 * 8] = *(const uint4*)(v + go);
  }
  __syncthreads();
  {
    float s = 0.f;
#pragma unroll
    for (int i = 0; i < 16; i++) s += bf2f(Ks[sqq * 16 + i][sdk]);
    ksump[sqq][sdk] = s;
  }
  f32x4 acc[4] = {};
#pragma unroll
  for (int ks = 0; ks < 2; ks++) {
    s16x8 af, bfr[4];
#pragma unroll
    for (int e = 0; e < 8; e++) af[e] = (short)Vs[ks * 32 + fk + e][w * 16 + fr];
#pragma unroll
    for (int j = 0; j < 4; j++)
#pragma unroll
      for (int e = 0; e < 8; e++) bfr[j][e] = (short)Ks[ks * 32 + fk + e][j * 16 + fr];
#pragma unroll
    for (int j = 0; j < 4; j++)
      acc[j] = __builtin_amdgcn_mfma_f32_16x16x32_bf16(af, bfr[j], acc[j], 0, 0, 0);
  }
  __syncthreads();
  {
    const int colL = lane & 15, rb = (lane >> 4) * 4;
#pragma unroll
    for (int j = 0; j < 4; j++)
#pragma unroll
      for (int r = 0; r < 4; r++)
        KVT[w * 16 + rb + r][j * 16 + colL] = f2bf(acc[j][r]);
  }
  if (tid < 64) ksum_s[tid] = ksump[0][tid] + ksump[1][tid] + ksump[2][tid] + ksump[3][tid];
  __syncthreads();
  if (tid < 64) {
    const u16* qp = q + base + (long)tid * 512;
    float d = 0.f;
#pragma unroll
    for (int c8 = 0; c8 < 8; c8++) {
      uint4 u = ((const uint4*)qp)[c8];
      const u16* us = (const u16*)&u;
#pragma unroll
      for (int e = 0; e < 8; e++) d += bf2f(us[e]) * ksum_s[c8 * 8 + e];
    }
    dinv[tid] = 0.5f / (d + 1e-6f);
  }
  f32x4 acc2[4] = {};
#pragma unroll
  for (int ks = 0; ks < 2; ks++) {
    s16x8 aq, bk[4];
    aq = *(const s16x8*)(q + base + (long)(w * 16 + fr) * 512 + ks * 32 + fk);
#pragma unroll
    for (int j = 0; j < 4; j++)
      bk[j] = *(const s16x8*)&KVT[j * 16 + fr][ks * 32 + fk];
#pragma unroll
    for (int j = 0; j < 4; j++)
      acc2[j] = __builtin_amdgcn_mfma_f32_16x16x32_bf16(aq, bk[j], acc2[j], 0, 0, 0);
  }
  __syncthreads();
  const int colL = lane & 15, rb = (lane >> 4) * 4;
#pragma unroll
  for (int r = 0; r < 4; r++) {
    int nr = w * 16 + rb + r;
    float inv = dinv[nr];
#pragma unroll
    for (int j = 0; j < 4; j++) {
      long o = base + (long)nr * 512 + j * 16 + colL;
      attc[o] = f2bf(bf2f(attc[o]) + acc2[j][r] * inv);
    }
  }
}

// ============================================================================
extern "C" void kernel_launch(void* const* d_in, const int* in_sizes, int n_in,
                              void* d_out, int out_size, void* d_ws, size_t ws_size,
                              hipStream_t stream) {
  const float* X    = (const float*)d_in[0];
  const float* Z    = (const float*)d_in[1];
  const float* n1   = (const float*)d_in[2];
  const float* n2   = (const float*)d_in[3];
  const float* n3   = (const float*)d_in[4];
  const float* nz   = (const float*)d_in[5];
  const float* a_wq = (const float*)d_in[6];
  const float* a_wk = (const float*)d_in[7];
  const float* a_wv = (const float*)d_in[8];
  const float* a_wo = (const float*)d_in[9];
  const float* c_wq = (const float*)d_in[10];
  const float* c_wk = (const float*)d_in[11];
  const float* c_wv = (const float*)d_in[12];
  const float* c_wo = (const float*)d_in[13];
  const float* f_w1 = (const float*)d_in[14];
  const float* f_w2 = (const float*)d_in[15];
  const float* f_w3 = (const float*)d_in[16];
  float* out = (float*)d_out;
  (void)ws_size; (void)in_sizes; (void)n_in; (void)out_size;

  char* p = (char*)d_ws;
  size_t off = 0;
  auto take = [&](size_t bytes) -> char* {
    char* r = p + off;
    off += (bytes + 255) & ~(size_t)255;
    return r;
  };
  // ws buffers: weights ~10.5 MiB + 3 x 64 MiB = ~203 MiB total.
  // w_aq/w_ak/w_av contiguous (each 512KB, already 256B-multiple) => they form
  // a stacked [1536][512] QKV weight for the fused projection. Same for c_*.
  u16* w_aq = (u16*)take(512 * 512 * 2);
  u16* w_ak = (u16*)take(512 * 512 * 2);
  u16* w_av = (u16*)take(512 * 512 * 2);
  u16* w_ao = (u16*)take(512 * 512 * 2);
  u16* w_cq = (u16*)take(512 * 512 * 2);
  u16* w_ck = (u16*)take(512 * 512 * 2);  // [k;v] stacked for EPI_KV
  u16* w_cv = (u16*)take(512 * 512 * 2);
  u16* w_co = (u16*)take(512 * 512 * 2);
  u16* w_f1 = (u16*)take(2048 * 512 * 2);
  u16* w_f3 = (u16*)take(2048 * 512 * 2);
  u16* w_f2 = (u16*)take(512 * 2048 * 2);
  u16* xn   = (u16*)take((size_t)65536 * 512 * 2);   // normed input; attc aliases
  u16* hbuf = (u16*)take((size_t)65536 * 512 * 2);   // bf16 residual h
  u16* qbuf = (u16*)take((size_t)65536 * 512 * 2);   // q; FFN hidden chunk aliases
  // d_out as scratch (128 MiB): k | v  (dead before phase 3 writes out)
  u16* kbuf = (u16*)d_out;
  u16* vbuf = (u16*)d_out + (size_t)65536 * 512;
  u16* attc = xn;     // alias: normed input dead once projections done
  u16* tslot = qbuf;  // FFN: [16384][2048] bf16 chunk = 64 MiB

  dim3 b256(256);
  dim3 gQKV(12, 512);  // Ns=1536 fused qkv -> 6144 blocks
  dim3 gKV(8, 512);    // Ns=1024 fused kv  -> 4096 blocks
  dim3 gP(4, 512);     // N=512, M=65536    -> 2048 blocks
  dim3 gU(16, 128);    // N=2048, M=16384   -> 2048 blocks
  dim3 gD(4, 128);     // N=512, M=16384    -> 512 blocks

  // weight prep
  wprep<512, 512><<<64, b256, 0, stream>>>(a_wq, w_aq);
  wprep<512, 512><<<64, b256, 0, stream>>>(a_wk, w_ak);
  wprep<512, 512><<<64, b256, 0, stream>>>(a_wv, w_av);
  wprep<512, 512><<<64, b256, 0, stream>>>(a_wo, w_ao);
  wprep<512, 512><<<64, b256, 0, stream>>>(c_wq, w_cq);
  wprep<512, 512><<<64, b256, 0, stream>>>(c_wk, w_ck);
  wprep<512, 512><<<64, b256, 0, stream>>>(c_wv, w_cv);
  wprep<512, 512><<<64, b256, 0, stream>>>(c_wo, w_co);
  wprep<512, 2048><<<256, b256, 0, stream>>>(f_w1, w_f1);
  wprep<512, 2048><<<256, b256, 0, stream>>>(f_w3, w_f3);
  wprep<2048, 512><<<256, b256, 0, stream>>>(f_w2, w_f2);

  // ---------------- Phase 1: h = X + SelfAtt(norm1(X)) ----------------------
  rmsnorm_f32<<<16384, b256, 0, stream>>>(X, n1, xn);
  gemm128<512, EPI_QKV><<<gQKV, b256, 0, stream>>>(xn, w_aq, qbuf, kbuf, vbuf, nullptr, 1536);
  att_mode1<<<2048, b256, 0, stream>>>(qbuf, kbuf, vbuf, attc);
  att_mode2<<<8192, b256, 0, stream>>>(qbuf, kbuf, vbuf, attc);
  gemm128<512, EPI_RESX><<<gP, b256, 0, stream>>>(attc, w_ao, hbuf, nullptr, nullptr, X, 512);

  // ---------------- Phase 2: h += CrossAtt(norm3(h), normz(Z)) --------------
  rmsnorm_bf16<<<16384, b256, 0, stream>>>(hbuf, n3, xn);
  gemm128<512, EPI_PHI><<<gP, b256, 0, stream>>>(xn, w_cq, qbuf, nullptr, nullptr, nullptr, 512);
  rmsnorm_f32<<<16384, b256, 0, stream>>>(Z, nz, xn);
  gemm128<512, EPI_KV><<<gKV, b256, 0, stream>>>(xn, w_ck, kbuf, vbuf, nullptr, nullptr, 1024);
  att_mode1<<<2048, b256, 0, stream>>>(qbuf, kbuf, vbuf, attc);
  att_mode2<<<8192, b256, 0, stream>>>(qbuf, kbuf, vbuf, attc);
  gemm128<512, EPI_RESH><<<gP, b256, 0, stream>>>(attc, w_co, hbuf, nullptr, nullptr, hbuf, 512);

  // ---------------- Phase 3: out = h + SwiGLU(norm2(h)) ---------------------
  rmsnorm_bf16<<<16384, b256, 0, stream>>>(hbuf, n2, xn);
  const int CH = 16384;
  for (int c = 0; c < 4; c++) {
    const size_t ro = (size_t)c * CH * 512;
    gemm128<512, EPI_BF16><<<gU, b256, 0, stream>>>(xn + ro, w_f1, tslot, nullptr, nullptr, nullptr, 2048);
    gemm128<512, EPI_SILUMUL><<<gU, b256, 0, stream>>>(xn + ro, w_f3, tslot, nullptr, nullptr, tslot, 2048);
    gemm128<2048, EPI_OUTF><<<gD, b256, 0, stream>>>(tslot, w_f2, out + ro, nullptr, nullptr, hbuf + ro, 512);
  }
}